// Round 13
// baseline (202.625 us; speedup 1.0000x reference)
//
#include <hip/hip_runtime.h>
#include <hip/hip_bf16.h>
#include <math.h>

#define CT 2596      // total functor count C
#define NF36 36
#define BB 32        // batch
#define NN 32        // seq len
#define VV 32000
#define DD 64
#define NEGF -1e9f
#define LOG2E 1.4426950408889634f
#define LN2F  0.6931471805599453f

typedef __attribute__((ext_vector_type(8))) short bf16x8;
typedef __attribute__((ext_vector_type(4))) float f32x4;

// bf16 helpers
__device__ __forceinline__ uint32_t f2bf_bits(float x) {
  union { float f; uint32_t u; } v; v.f = x;
  return (v.u + 0x7FFFu + ((v.u >> 16) & 1u)) >> 16;   // RNE
}
__device__ __forceinline__ float bflo(uint32_t u) {
  union { uint32_t u; float f; } v; v.u = u << 16; return v.f;
}
__device__ __forceinline__ float bfhi(uint32_t u) {
  union { uint32_t u; float f; } v; v.u = u & 0xFFFF0000u; return v.f;
}

// ---------------------------------------------------------------------------
// K1: fused front. ALL log-domain outputs are in BASE-2 units (×LOG2E).
// blocks [0,649): MLP -> split0/split1 (log2 units)
// [649,1649): vocab_W repack -> Wt (raw bf16) ; [1649,1681): token gather ->
// Bt (raw), vbt (×LOG2E) ; 1681: zero lseacc ; [1682,1718): rule rows ->
// Gl,Gr (log2 units, no split0) ; 1718: root scores -> root36 (log2 units)
__global__ __launch_bounds__(256) void k_front(
    const float* __restrict__ nt_emb,
    const float* __restrict__ sW1, const float* __restrict__ sb1,
    const float* __restrict__ r1W1, const float* __restrict__ r1b1,
    const float* __restrict__ r1W2, const float* __restrict__ r1b2,
    const float* __restrict__ r2W1, const float* __restrict__ r2b1,
    const float* __restrict__ r2W2, const float* __restrict__ r2b2,
    const float* __restrict__ sW2, const float* __restrict__ sb2,
    const float* __restrict__ vocab_W, const float* __restrict__ vocab_b,
    const int* __restrict__ x,
    const float* __restrict__ rule_W, const float* __restrict__ rule_b,
    const float* __restrict__ root_W, const float* __restrict__ root_b,
    float* __restrict__ split0, float* __restrict__ split1,
    uint4* __restrict__ Wt, uint4* __restrict__ Bt,
    float* __restrict__ vbt, float* __restrict__ lseacc,
    float* __restrict__ Gl, float* __restrict__ Gr,
    float* __restrict__ root36) {
  int blk = blockIdx.x;
  int tid = threadIdx.x;
  if (blk < 649) {
    __shared__ float hs[4][64], ts[4][64];
    __shared__ float WS[4096];
    int rl = tid >> 6, j = tid & 63;
    int c = blk * 4 + rl;
#define STAGE_W(Wp) for (int q = tid; q < 1024; q += 256) ((float4*)WS)[q] = ((const float4*)(Wp))[q];
    ts[rl][j] = nt_emb[(size_t)c * 64 + j];
    STAGE_W(sW1);
    __syncthreads();
    float a = sb1[j];
#pragma unroll 16
    for (int i = 0; i < 64; i++) a += ts[rl][i] * WS[i * 64 + j];
    __syncthreads();
    hs[rl][j] = a;
    STAGE_W(r1W1);
    __syncthreads();
    float u = r1b1[j];
#pragma unroll 16
    for (int i = 0; i < 64; i++) u += hs[rl][i] * WS[i * 64 + j];
    u = fmaxf(u, 0.f);
    __syncthreads();
    ts[rl][j] = u;
    STAGE_W(r1W2);
    __syncthreads();
    float w = r1b2[j];
#pragma unroll 16
    for (int i = 0; i < 64; i++) w += ts[rl][i] * WS[i * 64 + j];
    w = fmaxf(w, 0.f) + hs[rl][j];
    __syncthreads();
    hs[rl][j] = w;
    STAGE_W(r2W1);
    __syncthreads();
    u = r2b1[j];
#pragma unroll 16
    for (int i = 0; i < 64; i++) u += hs[rl][i] * WS[i * 64 + j];
    u = fmaxf(u, 0.f);
    __syncthreads();
    ts[rl][j] = u;
    STAGE_W(r2W2);
    __syncthreads();
    w = r2b2[j];
#pragma unroll 16
    for (int i = 0; i < 64; i++) w += ts[rl][i] * WS[i * 64 + j];
    w = fmaxf(w, 0.f) + hs[rl][j];
    __syncthreads();
    hs[rl][j] = w;
    __syncthreads();
    if (j < 2) {
      float o = sb2[j];
      for (int i = 0; i < 64; i++) o += hs[rl][i] * sW2[i * 2 + j];
      ts[rl][j] = o;
    }
    __syncthreads();
    if (j < 2) {
      float o0 = ts[rl][0], o1 = ts[rl][1];
      float mx = fmaxf(o0, o1);
      float l = mx + __logf(__expf(o0 - mx) + __expf(o1 - mx));
      if (j == 0) split0[c] = (o0 - l) * LOG2E;
      else        split1[c] = (o1 - l) * LOG2E;
    }
#undef STAGE_W
  } else if (blk < 1649) {
    int g = (blk - 649) * 256 + tid;
    int l = g & 63, f = (g >> 6) & 1, vt = g >> 7;
    int v = vt * 16 + (l & 15);
    int kb = f * 32 + 8 * (l >> 4);
    uint32_t d[4];
#pragma unroll
    for (int p = 0; p < 4; p++) {
      float a = vocab_W[(size_t)(kb + 2 * p) * VV + v];
      float b = vocab_W[(size_t)(kb + 2 * p + 1) * VV + v];
      d[p] = f2bf_bits(a) | (f2bf_bits(b) << 16);
    }
    uint4 o; o.x = d[0]; o.y = d[1]; o.z = d[2]; o.w = d[3];
    Wt[g] = o;
  } else if (blk < 1681) {
    int g = (blk - 1649) * 256 + tid;   // < 8192
    int l = g & 63, kf = (g >> 6) & 1, t = g >> 7;
    int j = t * 16 + (l & 15);
    int tok = x[j];
    int kb = kf * 32 + 8 * (l >> 4);
    uint32_t d[4];
#pragma unroll
    for (int p = 0; p < 4; p++) {
      float a = vocab_W[(size_t)(kb + 2 * p) * VV + tok];
      float b = vocab_W[(size_t)(kb + 2 * p + 1) * VV + tok];
      d[p] = f2bf_bits(a) | (f2bf_bits(b) << 16);
    }
    uint4 o; o.x = d[0]; o.y = d[1]; o.z = d[2]; o.w = d[3];
    Bt[g] = o;
    if (g < 1024) vbt[g] = vocab_b[x[g]] * LOG2E;
  } else if (blk == 1681) {
    for (int i = tid; i < CT; i += 256) lseacc[i] = 0.f;
  } else if (blk < 1718) {
    int res = blk - 1682;
    __shared__ float red[8];
    float v = (tid < 72) ? rule_W[res * 72 + tid] + rule_b[tid] : -1e30f;
    float m = v;
#pragma unroll
    for (int w = 32; w > 0; w >>= 1) m = fmaxf(m, __shfl_xor(m, w));
    if ((tid & 63) == 0) red[tid >> 6] = m;
    __syncthreads();
    m = fmaxf(fmaxf(red[0], red[1]), fmaxf(red[2], red[3]));
    float e = (tid < 72) ? __expf(v - m) : 0.f;
#pragma unroll
    for (int w = 32; w > 0; w >>= 1) e += __shfl_xor(e, w);
    if ((tid & 63) == 0) red[4 + (tid >> 6)] = e;
    __syncthreads();
    float l = m + __logf(red[4] + red[5] + red[6] + red[7]);
    if (tid < 36) {
      Gl[tid * 36 + res] = (rule_W[res * 72 + tid] + rule_b[tid] - l) * LOG2E;
      Gr[tid * 36 + res] = (rule_W[res * 72 + 36 + tid] + rule_b[36 + tid] - l) * LOG2E;
    }
  } else {
    __shared__ float lse4s;
    if (tid == 0) {
      float mx = -1e30f;
      for (int i = 0; i < 4; i++) mx = fmaxf(mx, root_W[i] + root_b[i]);
      float ss = 0.f;
      for (int i = 0; i < 4; i++) ss += __expf(root_W[i] + root_b[i] - mx);
      lse4s = mx + __logf(ss);
    }
    __syncthreads();
    if (tid < 36)
      root36[tid] = (((tid < 4) ? 0.f : NEGF) + root_W[tid] + root_b[tid] - lse4s) * LOG2E;
  }
}

// ---------------------------------------------------------------------------
// K4: MFMA GEMM + fused exp-sum over V. A scaled by LOG2E so acc is in log2
// units -> exp2f (native v_exp) with no per-logit mul.
__global__ __launch_bounds__(256) void k_lse_mfma(
    const float* __restrict__ nt_emb, const uint4* __restrict__ Wt,
    const float* __restrict__ vocab_b, float* __restrict__ lseacc) {
  int tid = threadIdx.x;
  int w = tid >> 6, l = tid & 63;
  int c0 = blockIdx.y * 128;
  int lrow = l & 15, lgrp = l >> 4;

  bf16x8 A[8][2];
#pragma unroll
  for (int ct = 0; ct < 8; ct++) {
    int row = c0 + ct * 16 + lrow;
#pragma unroll
    for (int kf = 0; kf < 2; kf++) {
      bf16x8 fr;
      if (row < CT) {
        const float4* src = (const float4*)(nt_emb + (size_t)row * 64 + kf * 32 + lgrp * 8);
        float4 s0 = src[0], s1 = src[1];
        fr[0] = (short)f2bf_bits(s0.x * LOG2E); fr[1] = (short)f2bf_bits(s0.y * LOG2E);
        fr[2] = (short)f2bf_bits(s0.z * LOG2E); fr[3] = (short)f2bf_bits(s0.w * LOG2E);
        fr[4] = (short)f2bf_bits(s1.x * LOG2E); fr[5] = (short)f2bf_bits(s1.y * LOG2E);
        fr[6] = (short)f2bf_bits(s1.z * LOG2E); fr[7] = (short)f2bf_bits(s1.w * LOG2E);
      } else {
#pragma unroll
        for (int e = 0; e < 8; e++) fr[e] = 0;
      }
      A[ct][kf] = fr;
    }
  }

  float sums[8][4];
#pragma unroll
  for (int ct = 0; ct < 8; ct++)
#pragma unroll
    for (int i = 0; i < 4; i++) sums[ct][i] = 0.f;

  int t0 = blockIdx.x * 80;
  for (int t = t0 + w; t < t0 + 80; t += 4) {
    union { uint4 u; bf16x8 h; } b0, b1;
    b0.u = Wt[(size_t)(t * 2) * 64 + l];
    b1.u = Wt[(size_t)(t * 2 + 1) * 64 + l];
    float vb = vocab_b[t * 16 + lrow] * LOG2E;
#pragma unroll
    for (int ct = 0; ct < 8; ct++) {
      f32x4 acc = {0.f, 0.f, 0.f, 0.f};
      acc = __builtin_amdgcn_mfma_f32_16x16x32_bf16(A[ct][0], b0.h, acc, 0, 0, 0);
      acc = __builtin_amdgcn_mfma_f32_16x16x32_bf16(A[ct][1], b1.h, acc, 0, 0, 0);
#pragma unroll
      for (int i = 0; i < 4; i++) sums[ct][i] += exp2f(acc[i] + vb);
    }
  }

#pragma unroll
  for (int ct = 0; ct < 8; ct++)
#pragma unroll
    for (int i = 0; i < 4; i++) {
      float v = sums[ct][i];
      v += __shfl_xor(v, 1);
      v += __shfl_xor(v, 2);
      v += __shfl_xor(v, 4);
      v += __shfl_xor(v, 8);
      sums[ct][i] = v;
    }
  if (lrow == 0) {
#pragma unroll
    for (int ct = 0; ct < 8; ct++)
#pragma unroll
      for (int i = 0; i < 4; i++) {
        int row = c0 + ct * 16 + lgrp * 4 + i;
        if (row < CT) atomicAdd(&lseacc[row], sums[ct][i]);
      }
  }
}

// ---------------------------------------------------------------------------
// K5: beta1 via MFMA (log2 units: A ×LOG2E, vbt pre-scaled, log2f(lseacc)).
__global__ __launch_bounds__(256) void k_beta1_mfma(
    const float* __restrict__ nt_emb, const uint4* __restrict__ Bt,
    const float* __restrict__ vbt, const float* __restrict__ lseacc,
    const float* __restrict__ split1, float* __restrict__ beta1) {
  int tid = threadIdx.x;
  int w = tid >> 6, l = tid & 63;
  int c0 = blockIdx.x * 64;
  int lrow = l & 15, lgrp = l >> 4;
  __shared__ float addS[64];
  if (tid < 64) {
    int row = c0 + tid;
    addS[tid] = (row < CT) ? (split1[row] - __log2f(lseacc[row])) : 0.f;
  }

  bf16x8 A[4][2];
#pragma unroll
  for (int ct = 0; ct < 4; ct++) {
    int row = c0 + ct * 16 + lrow;
#pragma unroll
    for (int kf = 0; kf < 2; kf++) {
      bf16x8 fr;
      if (row < CT) {
        const float4* src = (const float4*)(nt_emb + (size_t)row * 64 + kf * 32 + lgrp * 8);
        float4 s0 = src[0], s1 = src[1];
        fr[0] = (short)f2bf_bits(s0.x * LOG2E); fr[1] = (short)f2bf_bits(s0.y * LOG2E);
        fr[2] = (short)f2bf_bits(s0.z * LOG2E); fr[3] = (short)f2bf_bits(s0.w * LOG2E);
        fr[4] = (short)f2bf_bits(s1.x * LOG2E); fr[5] = (short)f2bf_bits(s1.y * LOG2E);
        fr[6] = (short)f2bf_bits(s1.z * LOG2E); fr[7] = (short)f2bf_bits(s1.w * LOG2E);
      } else {
#pragma unroll
        for (int e = 0; e < 8; e++) fr[e] = 0;
      }
      A[ct][kf] = fr;
    }
  }
  __syncthreads();
  float addv[4][4];
#pragma unroll
  for (int ct = 0; ct < 4; ct++)
#pragma unroll
    for (int i = 0; i < 4; i++) addv[ct][i] = addS[ct * 16 + lgrp * 4 + i];

  int t0 = blockIdx.y * 8;
  for (int t = t0 + w; t < t0 + 8; t += 4) {
    union { uint4 u; bf16x8 h; } b0, b1;
    b0.u = Bt[t * 128 + l];
    b1.u = Bt[t * 128 + 64 + l];
    int j = t * 16 + lrow;
    float vb = vbt[j];
    int jc = (j & 31) * 32 + (j >> 5);
    float* outb = beta1 + (size_t)jc * CT;
#pragma unroll
    for (int ct = 0; ct < 4; ct++) {
      f32x4 acc = {0.f, 0.f, 0.f, 0.f};
      acc = __builtin_amdgcn_mfma_f32_16x16x32_bf16(A[ct][0], b0.h, acc, 0, 0, 0);
      acc = __builtin_amdgcn_mfma_f32_16x16x32_bf16(A[ct][1], b1.h, acc, 0, 0, 0);
      int r0 = c0 + ct * 16 + lgrp * 4;
      if (r0 + 3 < CT) {
        float4 o;
        o.x = acc[0] + vb + addv[ct][0];
        o.y = acc[1] + vb + addv[ct][1];
        o.z = acc[2] + vb + addv[ct][2];
        o.w = acc[3] + vb + addv[ct][3];
        *(float4*)(outb + r0) = o;
      } else {
        for (int i = 0; i < 4; i++)
          if (r0 + i < CT) outb[r0 + i] = acc[i] + vb + addv[ct][i];
      }
    }
  }
}

// ---------------------------------------------------------------------------
// K6: EXP-space edge tables, bf16 packed, [sb][res][20 u32]. All inputs in
// log2 units -> exp2f.
__global__ __launch_bounds__(256) void k_edge(
    const float* __restrict__ beta1, const int* __restrict__ lf_t,
    const int* __restrict__ rf_t, const float* __restrict__ Gl,
    const float* __restrict__ Gr, const float* __restrict__ split0,
    uint32_t* __restrict__ elB, uint32_t* __restrict__ erB) {
  int sb = blockIdx.x;
  const float* brow = beta1 + (size_t)sb * CT;
  size_t ob = (size_t)sb * 720;
  for (int wd = threadIdx.x; wd < 720; wd += 256) {
    int res = wd / 20, p = wd - res * 20;
    float s0 = split0[res];
    int a0 = 2 * p, a1 = 2 * p + 1;
    uint32_t l0 = 0, l1 = 0, r0 = 0, r1 = 0;
    if (a0 < 36) {
      int i0 = a0 * 36 + res;
      l0 = f2bf_bits(exp2f(brow[lf_t[i0]] + Gr[i0] + s0));
      r0 = f2bf_bits(exp2f(brow[rf_t[i0]] + Gl[i0] + s0));
    }
    if (a1 < 36) {
      int i1 = a1 * 36 + res;
      l1 = f2bf_bits(exp2f(brow[lf_t[i1]] + Gr[i1] + s0));
      r1 = f2bf_bits(exp2f(brow[rf_t[i1]] + Gl[i1] + s0));
    }
    elB[ob + wd] = l0 | (l1 << 16);
    erB[ob + wd] = r0 | (r1 << 16);
  }
}

// ---------------------------------------------------------------------------
// K7: CKY inside pass, EXP(base-2)-space, bf16 edge tables. R6 structure
// (95us, 4x reproduced) + R12 mid-batching + this round: log2 domain and
// GUARDED atomicMax (read LDS first, atomic only when larger — candb is
// monotone so the guard is race-safe). NO register caching (spills, R7/R10).
__global__ __launch_bounds__(1024, 4) void k_cky(
    const float* __restrict__ beta1, const uint32_t* __restrict__ elB,
    const uint32_t* __restrict__ erB, const float* __restrict__ Gl,
    const float* __restrict__ Gr, const float* __restrict__ split0,
    const float* __restrict__ root36, float* __restrict__ out) {
  __shared__ __align__(16) float D[19008];
  __shared__ float Mt[528];
  __shared__ __align__(16) float PA[1280], PB[1280];      // stride 40, padded
  __shared__ __align__(16) float Ec1lT[512], Ec1rT[512];  // [s][res][a]
  __shared__ __align__(16) float eGlT[16], eGrT[16];      // [res][a]
  __shared__ unsigned int candb[2][33];
  __shared__ float MIDacc[128];

  int b = blockIdx.x, tid = threadIdx.x;

  if (tid < 66) candb[tid / 33][tid % 33] = 0u;
  if (tid < 32) Mt[tid] = 0.f;
  if (tid < 16) {
    int res = tid >> 2, a = tid & 3;
    float s0 = split0[res];
    eGlT[tid] = exp2f(Gl[a * 36 + res] + s0);
    eGrT[tid] = exp2f(Gr[a * 36 + res] + s0);
  }
  for (int i = tid; i < 1280; i += 1024) { PA[i] = 0.f; PB[i] = 0.f; }
  __syncthreads();
  for (int i = tid; i < 32 * 36; i += 1024) {
    int s = i / 36;
    float v = exp2f(beta1[(size_t)(s * 32 + b) * CT + (i - s * 36)]);
    D[i] = v;
    unsigned int vb_ = __float_as_uint(v);
    if (vb_ > candb[1][s]) atomicMax(&candb[1][s], vb_);
  }
  __syncthreads();
  for (int i = tid; i < 512; i += 1024) {
    int s = i >> 4, rr = (i >> 2) & 3, a = i & 3;
    float d1 = D[s * 36 + a];
    Ec1lT[i] = d1 * eGlT[rr * 4 + a];
    Ec1rT[i] = d1 * eGrT[rr * 4 + a];
  }
  __syncthreads();

  for (int L = 2; L <= 32; L++) {
    int S = 33 - L;
    int offL  = 36 * (((L - 1) * (66 - L)) >> 1);
    int offP  = 36 * (((L - 2) * (67 - L)) >> 1);
    int offML = ((L - 1) * (66 - L)) >> 1;
    int offMP = ((L - 2) * (67 - L)) >> 1;
    int par = L & 1, parP = par ^ 1;

    // ---- phase A: scale prev level into PA/PB; zero candb[par], MIDacc
    if (tid < 33) candb[par][tid] = 0u;
    if (tid >= 64 && tid < 192) MIDacc[tid - 64] = 0.f;
    int totA = S * 36;
    for (int o = tid; o < totA; o += 1024) {
      int s = o / 36, j = o - s * 36;
      float MtA = Mt[offMP + s], MtB = Mt[offMP + s + 1];
      float cA = MtA + __log2f(fmaxf(__uint_as_float(candb[parP][s]), 1e-37f));
      float cB = MtB + __log2f(fmaxf(__uint_as_float(candb[parP][s + 1]), 1e-37f));
      float Mn = fmaxf(cA, cB);
      PA[s * 40 + j] = D[offP + s * 36 + j] * exp2f(MtA - Mn);
      PB[s * 40 + j] = D[offP + (s + 1) * 36 + j] * exp2f(MtB - Mn);
      if (j == 0) Mt[offML + s] = Mn;
    }
    __syncthreads();

    // ---- phase 2: mains + mids (4 k-splits per mid item)
    int tot = S * 36;
    int ngrp = (L >= 4) ? ((L - 3 + 3) >> 2) : 0;   // ceil((L-3)/4)
    int nmid = 4 * S * ngrp;
    int W = tot + nmid;
    for (int o = tid; o < W; o += 1024) {
      if (o < tot) {
        int s = o / 36, res = o - s * 36;
        const uint4* el4 = (const uint4*)(elB + (size_t)(s * 32 + b) * 720 + res * 20);
        const uint4* er4 = (const uint4*)(erB + (size_t)((s + L - 1) * 32 + b) * 720 + res * 20);
        const float4* pB4 = (const float4*)(PB + s * 40);
        const float4* pA4 = (const float4*)(PA + s * 40);
        float a0 = 0.f, a1 = 0.f, a2 = 0.f, a3 = 0.f;
#pragma unroll
        for (int q = 0; q < 5; q++) {
          uint4 u = el4[q];
          float4 p0 = pB4[2 * q], p1 = pB4[2 * q + 1];
          a0 = fmaf(bflo(u.x), p0.x, a0); a1 = fmaf(bfhi(u.x), p0.y, a1);
          a2 = fmaf(bflo(u.y), p0.z, a2); a3 = fmaf(bfhi(u.y), p0.w, a3);
          a0 = fmaf(bflo(u.z), p1.x, a0); a1 = fmaf(bfhi(u.z), p1.y, a1);
          a2 = fmaf(bflo(u.w), p1.z, a2); a3 = fmaf(bfhi(u.w), p1.w, a3);
          uint4 v = er4[q];
          float4 q0 = pA4[2 * q], q1 = pA4[2 * q + 1];
          a0 = fmaf(bflo(v.x), q0.x, a0); a1 = fmaf(bfhi(v.x), q0.y, a1);
          a2 = fmaf(bflo(v.y), q0.z, a2); a3 = fmaf(bfhi(v.y), q0.w, a3);
          a0 = fmaf(bflo(v.z), q1.x, a0); a1 = fmaf(bfhi(v.z), q1.y, a1);
          a2 = fmaf(bflo(v.w), q1.z, a2); a3 = fmaf(bfhi(v.w), q1.w, a3);
        }
        if (res < 4 && L >= 3) {
          const float4* ecl = (const float4*)(Ec1lT + s * 16 + res * 4);
          const float4* ecr = (const float4*)(Ec1rT + (s + L - 1) * 16 + res * 4);
          float4 e0 = ecl[0], pb = pB4[5 + res];
          float4 e1 = ecr[0], pa = pA4[1 + res];
          a0 = fmaf(e0.x, pb.x, a0); a1 = fmaf(e0.y, pb.y, a1);
          a2 = fmaf(e0.z, pb.z, a2); a3 = fmaf(e0.w, pb.w, a3);
          a0 = fmaf(e1.x, pa.x, a0); a1 = fmaf(e1.y, pa.y, a1);
          a2 = fmaf(e1.z, pa.z, a2); a3 = fmaf(e1.w, pa.w, a3);
        }
        float val = (a0 + a1) + (a2 + a3);
        D[offL + o] = val;
        unsigned int vb_ = __float_as_uint(val);
        if (vb_ > candb[par][s]) atomicMax(&candb[par][s], vb_);
      } else {
        int o2 = o - tot;
        int grp = o2 / (4 * S);
        int rem = o2 - grp * 4 * S;
        int s = rem >> 2, res = rem & 3;
        float4 egl = ((const float4*)eGlT)[res];
        float4 egr = ((const float4*)eGrT)[res];
        float Mn = Mt[offML + s];
        float mv = 0.f;
        int kbase = grp * 4 + 2;
#pragma unroll 1
        for (int kk = 0; kk < 4; kk++) {
          int k = kbase + kk;
          if (k > L - 2) break;
          int lk = L - k;
          int tk = ((k - 1) * (66 - k)) >> 1;
          int tl = ((lk - 1) * (66 - lk)) >> 1;
          const float4* Dk4 = (const float4*)(D + 36 * tk + s * 36);
          const float4* Dl4 = (const float4*)(D + 36 * tl + (s + k) * 36);
          float4 dk0 = Dk4[0], dkh = Dk4[1 + res];
          float4 dl0 = Dl4[0], dlh = Dl4[5 + res];
          float f = exp2f(Mt[tk + s] + Mt[tl + s + k] - Mn);
          float sub = dk0.x * dlh.x * egl.x + dk0.y * dlh.y * egl.y
                    + dk0.z * dlh.z * egl.z + dk0.w * dlh.w * egl.w
                    + dl0.x * dkh.x * egr.x + dl0.y * dkh.y * egr.y
                    + dl0.z * dkh.z * egr.z + dl0.w * dkh.w * egr.w;
          mv = fmaf(f, sub, mv);
        }
        atomicAdd(&MIDacc[rem], mv);
      }
    }
    __syncthreads();

    // ---- phase 3: merge mids into D (res<4 columns)
    if (L >= 4) {
      for (int o = tid; o < 4 * S; o += 1024) {
        int s = o >> 2;
        float nv = D[offL + s * 36 + (o & 3)] + MIDacc[o];
        D[offL + s * 36 + (o & 3)] = nv;
        unsigned int vb_ = __float_as_uint(nv);
        if (vb_ > candb[par][s]) atomicMax(&candb[par][s], vb_);
      }
    }
    __syncthreads();
  }

  int wid = tid >> 6, lane = tid & 63;
  if (wid == 0) {
    int off32 = 36 * ((31 * 34) >> 1);
    float v = (lane < 36) ? D[off32 + lane] * exp2f(root36[lane]) : 0.f;
#pragma unroll
    for (int w = 32; w > 0; w >>= 1) v += __shfl_xor(v, w);
    if (lane == 0) out[b] = -(Mt[527] + __log2f(v)) * LN2F;
  }
}

// ---------------------------------------------------------------------------
extern "C" void kernel_launch(void* const* d_in, const int* in_sizes, int n_in,
                              void* d_out, int out_size, void* d_ws, size_t ws_size,
                              hipStream_t stream) {
  const int*   x       = (const int*)d_in[0];
  const int*   lf_t    = (const int*)d_in[1];
  const int*   rf_t    = (const int*)d_in[2];
  const float* root_W  = (const float*)d_in[3];
  const float* root_b  = (const float*)d_in[4];
  const float* rule_W  = (const float*)d_in[5];
  const float* rule_b  = (const float*)d_in[6];
  const float* nt_emb  = (const float*)d_in[7];
  const float* sW1     = (const float*)d_in[8];
  const float* sb1     = (const float*)d_in[9];
  const float* r1W1    = (const float*)d_in[10];
  const float* r1b1    = (const float*)d_in[11];
  const float* r1W2    = (const float*)d_in[12];
  const float* r1b2    = (const float*)d_in[13];
  const float* r2W1    = (const float*)d_in[14];
  const float* r2b1    = (const float*)d_in[15];
  const float* r2W2    = (const float*)d_in[16];
  const float* r2b2    = (const float*)d_in[17];
  const float* sW2     = (const float*)d_in[18];
  const float* sb2     = (const float*)d_in[19];
  const float* vocab_W = (const float*)d_in[20];
  const float* vocab_b = (const float*)d_in[21];
  float* outp = (float*)d_out;

  float* ws = (float*)d_ws;
  float* split0 = ws;                         // 2596
  float* split1 = ws + 2596;                  // 2596
  float* Gl     = ws + 5192;                  // 1296
  float* Gr     = ws + 6488;                  // 1296
  float* root36 = ws + 7784;                  // 64
  float* lseacc = ws + 7848;                  // 2596 (pad to 2600)
  float* vbt    = ws + 10448;                 // 1024
  float* beta1  = ws + 11472;                 // 2658304 -> end 2669776
  uint32_t* elB = (uint32_t*)(ws + 2669776);  // 737280 -> end 3407056
  uint32_t* erB = (uint32_t*)(ws + 3407056);  // 737280 -> end 4144336
  // Wt overlays elB/erB region: consumed by k_lse_mfma BEFORE k_edge writes.
  uint4* Wt     = (uint4*)(ws + 2669776);     // 256000 uint4
  uint4* Bt     = (uint4*)(ws + 4144336);     // 8192 uint4 -> end 4177104

  k_front<<<1719, 256, 0, stream>>>(nt_emb, sW1, sb1, r1W1, r1b1, r1W2, r1b2,
                                    r2W1, r2b1, r2W2, r2b2, sW2, sb2,
                                    vocab_W, vocab_b, x,
                                    rule_W, rule_b, root_W, root_b,
                                    split0, split1, Wt, Bt, vbt, lseacc,
                                    Gl, Gr, root36);
  k_lse_mfma<<<dim3(25, 21), 256, 0, stream>>>(nt_emb, Wt, vocab_b, lseacc);
  k_beta1_mfma<<<dim3(41, 8), 256, 0, stream>>>(nt_emb, Bt, vbt, lseacc, split1, beta1);
  k_edge<<<1024, 256, 0, stream>>>(beta1, lf_t, rf_t, Gl, Gr, split0, elB, erB);
  k_cky<<<32, 1024, 0, stream>>>(beta1, elB, erB, Gl, Gr, split0, root36, outp);
}

// Round 14
// 187.050 us; speedup vs baseline: 1.0833x; 1.0833x over previous
//
#include <hip/hip_runtime.h>
#include <hip/hip_bf16.h>
#include <math.h>

#define CT 2596      // total functor count C
#define NF36 36
#define BB 32        // batch
#define NN 32        // seq len
#define VV 32000
#define DD 64
#define NEGF -1e9f
#define LOG2E 1.4426950408889634f
#define LN2F  0.6931471805599453f

// hardware v_exp_f32 is base-2: direct map, no libcall, no extra mul
#define EXP2F(x) __builtin_amdgcn_exp2f(x)

typedef __attribute__((ext_vector_type(8))) short bf16x8;
typedef __attribute__((ext_vector_type(4))) float f32x4;

// bf16 helpers
__device__ __forceinline__ uint32_t f2bf_bits(float x) {
  union { float f; uint32_t u; } v; v.f = x;
  return (v.u + 0x7FFFu + ((v.u >> 16) & 1u)) >> 16;   // RNE
}
__device__ __forceinline__ float bflo(uint32_t u) {
  union { uint32_t u; float f; } v; v.u = u << 16; return v.f;
}
__device__ __forceinline__ float bfhi(uint32_t u) {
  union { uint32_t u; float f; } v; v.u = u & 0xFFFF0000u; return v.f;
}

// ---------------------------------------------------------------------------
// K1: fused front. ALL log-domain outputs are in BASE-2 units (×LOG2E).
__global__ __launch_bounds__(256) void k_front(
    const float* __restrict__ nt_emb,
    const float* __restrict__ sW1, const float* __restrict__ sb1,
    const float* __restrict__ r1W1, const float* __restrict__ r1b1,
    const float* __restrict__ r1W2, const float* __restrict__ r1b2,
    const float* __restrict__ r2W1, const float* __restrict__ r2b1,
    const float* __restrict__ r2W2, const float* __restrict__ r2b2,
    const float* __restrict__ sW2, const float* __restrict__ sb2,
    const float* __restrict__ vocab_W, const float* __restrict__ vocab_b,
    const int* __restrict__ x,
    const float* __restrict__ rule_W, const float* __restrict__ rule_b,
    const float* __restrict__ root_W, const float* __restrict__ root_b,
    float* __restrict__ split0, float* __restrict__ split1,
    uint4* __restrict__ Wt, uint4* __restrict__ Bt,
    float* __restrict__ vbt, float* __restrict__ lseacc,
    float* __restrict__ Gl, float* __restrict__ Gr,
    float* __restrict__ root36) {
  int blk = blockIdx.x;
  int tid = threadIdx.x;
  if (blk < 649) {
    __shared__ float hs[4][64], ts[4][64];
    __shared__ float WS[4096];
    int rl = tid >> 6, j = tid & 63;
    int c = blk * 4 + rl;
#define STAGE_W(Wp) for (int q = tid; q < 1024; q += 256) ((float4*)WS)[q] = ((const float4*)(Wp))[q];
    ts[rl][j] = nt_emb[(size_t)c * 64 + j];
    STAGE_W(sW1);
    __syncthreads();
    float a = sb1[j];
#pragma unroll 16
    for (int i = 0; i < 64; i++) a += ts[rl][i] * WS[i * 64 + j];
    __syncthreads();
    hs[rl][j] = a;
    STAGE_W(r1W1);
    __syncthreads();
    float u = r1b1[j];
#pragma unroll 16
    for (int i = 0; i < 64; i++) u += hs[rl][i] * WS[i * 64 + j];
    u = fmaxf(u, 0.f);
    __syncthreads();
    ts[rl][j] = u;
    STAGE_W(r1W2);
    __syncthreads();
    float w = r1b2[j];
#pragma unroll 16
    for (int i = 0; i < 64; i++) w += ts[rl][i] * WS[i * 64 + j];
    w = fmaxf(w, 0.f) + hs[rl][j];
    __syncthreads();
    hs[rl][j] = w;
    STAGE_W(r2W1);
    __syncthreads();
    u = r2b1[j];
#pragma unroll 16
    for (int i = 0; i < 64; i++) u += hs[rl][i] * WS[i * 64 + j];
    u = fmaxf(u, 0.f);
    __syncthreads();
    ts[rl][j] = u;
    STAGE_W(r2W2);
    __syncthreads();
    w = r2b2[j];
#pragma unroll 16
    for (int i = 0; i < 64; i++) w += ts[rl][i] * WS[i * 64 + j];
    w = fmaxf(w, 0.f) + hs[rl][j];
    __syncthreads();
    hs[rl][j] = w;
    __syncthreads();
    if (j < 2) {
      float o = sb2[j];
      for (int i = 0; i < 64; i++) o += hs[rl][i] * sW2[i * 2 + j];
      ts[rl][j] = o;
    }
    __syncthreads();
    if (j < 2) {
      float o0 = ts[rl][0], o1 = ts[rl][1];
      float mx = fmaxf(o0, o1);
      float l = mx + __logf(__expf(o0 - mx) + __expf(o1 - mx));
      if (j == 0) split0[c] = (o0 - l) * LOG2E;
      else        split1[c] = (o1 - l) * LOG2E;
    }
#undef STAGE_W
  } else if (blk < 1649) {
    int g = (blk - 649) * 256 + tid;
    int l = g & 63, f = (g >> 6) & 1, vt = g >> 7;
    int v = vt * 16 + (l & 15);
    int kb = f * 32 + 8 * (l >> 4);
    uint32_t d[4];
#pragma unroll
    for (int p = 0; p < 4; p++) {
      float a = vocab_W[(size_t)(kb + 2 * p) * VV + v];
      float b = vocab_W[(size_t)(kb + 2 * p + 1) * VV + v];
      d[p] = f2bf_bits(a) | (f2bf_bits(b) << 16);
    }
    uint4 o; o.x = d[0]; o.y = d[1]; o.z = d[2]; o.w = d[3];
    Wt[g] = o;
  } else if (blk < 1681) {
    int g = (blk - 1649) * 256 + tid;   // < 8192
    int l = g & 63, kf = (g >> 6) & 1, t = g >> 7;
    int j = t * 16 + (l & 15);
    int tok = x[j];
    int kb = kf * 32 + 8 * (l >> 4);
    uint32_t d[4];
#pragma unroll
    for (int p = 0; p < 4; p++) {
      float a = vocab_W[(size_t)(kb + 2 * p) * VV + tok];
      float b = vocab_W[(size_t)(kb + 2 * p + 1) * VV + tok];
      d[p] = f2bf_bits(a) | (f2bf_bits(b) << 16);
    }
    uint4 o; o.x = d[0]; o.y = d[1]; o.z = d[2]; o.w = d[3];
    Bt[g] = o;
    if (g < 1024) vbt[g] = vocab_b[x[g]] * LOG2E;
  } else if (blk == 1681) {
    for (int i = tid; i < CT; i += 256) lseacc[i] = 0.f;
  } else if (blk < 1718) {
    int res = blk - 1682;
    __shared__ float red[8];
    float v = (tid < 72) ? rule_W[res * 72 + tid] + rule_b[tid] : -1e30f;
    float m = v;
#pragma unroll
    for (int w = 32; w > 0; w >>= 1) m = fmaxf(m, __shfl_xor(m, w));
    if ((tid & 63) == 0) red[tid >> 6] = m;
    __syncthreads();
    m = fmaxf(fmaxf(red[0], red[1]), fmaxf(red[2], red[3]));
    float e = (tid < 72) ? __expf(v - m) : 0.f;
#pragma unroll
    for (int w = 32; w > 0; w >>= 1) e += __shfl_xor(e, w);
    if ((tid & 63) == 0) red[4 + (tid >> 6)] = e;
    __syncthreads();
    float l = m + __logf(red[4] + red[5] + red[6] + red[7]);
    if (tid < 36) {
      Gl[tid * 36 + res] = (rule_W[res * 72 + tid] + rule_b[tid] - l) * LOG2E;
      Gr[tid * 36 + res] = (rule_W[res * 72 + 36 + tid] + rule_b[36 + tid] - l) * LOG2E;
    }
  } else {
    __shared__ float lse4s;
    if (tid == 0) {
      float mx = -1e30f;
      for (int i = 0; i < 4; i++) mx = fmaxf(mx, root_W[i] + root_b[i]);
      float ss = 0.f;
      for (int i = 0; i < 4; i++) ss += __expf(root_W[i] + root_b[i] - mx);
      lse4s = mx + __logf(ss);
    }
    __syncthreads();
    if (tid < 36)
      root36[tid] = (((tid < 4) ? 0.f : NEGF) + root_W[tid] + root_b[tid] - lse4s) * LOG2E;
  }
}

// ---------------------------------------------------------------------------
// K4: MFMA GEMM + fused exp-sum over V. acc in log2 units -> raw v_exp_f32.
__global__ __launch_bounds__(256) void k_lse_mfma(
    const float* __restrict__ nt_emb, const uint4* __restrict__ Wt,
    const float* __restrict__ vocab_b, float* __restrict__ lseacc) {
  int tid = threadIdx.x;
  int w = tid >> 6, l = tid & 63;
  int c0 = blockIdx.y * 128;
  int lrow = l & 15, lgrp = l >> 4;

  bf16x8 A[8][2];
#pragma unroll
  for (int ct = 0; ct < 8; ct++) {
    int row = c0 + ct * 16 + lrow;
#pragma unroll
    for (int kf = 0; kf < 2; kf++) {
      bf16x8 fr;
      if (row < CT) {
        const float4* src = (const float4*)(nt_emb + (size_t)row * 64 + kf * 32 + lgrp * 8);
        float4 s0 = src[0], s1 = src[1];
        fr[0] = (short)f2bf_bits(s0.x * LOG2E); fr[1] = (short)f2bf_bits(s0.y * LOG2E);
        fr[2] = (short)f2bf_bits(s0.z * LOG2E); fr[3] = (short)f2bf_bits(s0.w * LOG2E);
        fr[4] = (short)f2bf_bits(s1.x * LOG2E); fr[5] = (short)f2bf_bits(s1.y * LOG2E);
        fr[6] = (short)f2bf_bits(s1.z * LOG2E); fr[7] = (short)f2bf_bits(s1.w * LOG2E);
      } else {
#pragma unroll
        for (int e = 0; e < 8; e++) fr[e] = 0;
      }
      A[ct][kf] = fr;
    }
  }

  float sums[8][4];
#pragma unroll
  for (int ct = 0; ct < 8; ct++)
#pragma unroll
    for (int i = 0; i < 4; i++) sums[ct][i] = 0.f;

  int t0 = blockIdx.x * 80;
  for (int t = t0 + w; t < t0 + 80; t += 4) {
    union { uint4 u; bf16x8 h; } b0, b1;
    b0.u = Wt[(size_t)(t * 2) * 64 + l];
    b1.u = Wt[(size_t)(t * 2 + 1) * 64 + l];
    float vb = vocab_b[t * 16 + lrow] * LOG2E;
#pragma unroll
    for (int ct = 0; ct < 8; ct++) {
      f32x4 acc = {0.f, 0.f, 0.f, 0.f};
      acc = __builtin_amdgcn_mfma_f32_16x16x32_bf16(A[ct][0], b0.h, acc, 0, 0, 0);
      acc = __builtin_amdgcn_mfma_f32_16x16x32_bf16(A[ct][1], b1.h, acc, 0, 0, 0);
#pragma unroll
      for (int i = 0; i < 4; i++) sums[ct][i] += EXP2F(acc[i] + vb);
    }
  }

#pragma unroll
  for (int ct = 0; ct < 8; ct++)
#pragma unroll
    for (int i = 0; i < 4; i++) {
      float v = sums[ct][i];
      v += __shfl_xor(v, 1);
      v += __shfl_xor(v, 2);
      v += __shfl_xor(v, 4);
      v += __shfl_xor(v, 8);
      sums[ct][i] = v;
    }
  if (lrow == 0) {
#pragma unroll
    for (int ct = 0; ct < 8; ct++)
#pragma unroll
      for (int i = 0; i < 4; i++) {
        int row = c0 + ct * 16 + lgrp * 4 + i;
        if (row < CT) atomicAdd(&lseacc[row], sums[ct][i]);
      }
  }
}

// ---------------------------------------------------------------------------
// K5: beta1 via MFMA (log2 units).
__global__ __launch_bounds__(256) void k_beta1_mfma(
    const float* __restrict__ nt_emb, const uint4* __restrict__ Bt,
    const float* __restrict__ vbt, const float* __restrict__ lseacc,
    const float* __restrict__ split1, float* __restrict__ beta1) {
  int tid = threadIdx.x;
  int w = tid >> 6, l = tid & 63;
  int c0 = blockIdx.x * 64;
  int lrow = l & 15, lgrp = l >> 4;
  __shared__ float addS[64];
  if (tid < 64) {
    int row = c0 + tid;
    addS[tid] = (row < CT) ? (split1[row] - __log2f(lseacc[row])) : 0.f;
  }

  bf16x8 A[4][2];
#pragma unroll
  for (int ct = 0; ct < 4; ct++) {
    int row = c0 + ct * 16 + lrow;
#pragma unroll
    for (int kf = 0; kf < 2; kf++) {
      bf16x8 fr;
      if (row < CT) {
        const float4* src = (const float4*)(nt_emb + (size_t)row * 64 + kf * 32 + lgrp * 8);
        float4 s0 = src[0], s1 = src[1];
        fr[0] = (short)f2bf_bits(s0.x * LOG2E); fr[1] = (short)f2bf_bits(s0.y * LOG2E);
        fr[2] = (short)f2bf_bits(s0.z * LOG2E); fr[3] = (short)f2bf_bits(s0.w * LOG2E);
        fr[4] = (short)f2bf_bits(s1.x * LOG2E); fr[5] = (short)f2bf_bits(s1.y * LOG2E);
        fr[6] = (short)f2bf_bits(s1.z * LOG2E); fr[7] = (short)f2bf_bits(s1.w * LOG2E);
      } else {
#pragma unroll
        for (int e = 0; e < 8; e++) fr[e] = 0;
      }
      A[ct][kf] = fr;
    }
  }
  __syncthreads();
  float addv[4][4];
#pragma unroll
  for (int ct = 0; ct < 4; ct++)
#pragma unroll
    for (int i = 0; i < 4; i++) addv[ct][i] = addS[ct * 16 + lgrp * 4 + i];

  int t0 = blockIdx.y * 8;
  for (int t = t0 + w; t < t0 + 8; t += 4) {
    union { uint4 u; bf16x8 h; } b0, b1;
    b0.u = Bt[t * 128 + l];
    b1.u = Bt[t * 128 + 64 + l];
    int j = t * 16 + lrow;
    float vb = vbt[j];
    int jc = (j & 31) * 32 + (j >> 5);
    float* outb = beta1 + (size_t)jc * CT;
#pragma unroll
    for (int ct = 0; ct < 4; ct++) {
      f32x4 acc = {0.f, 0.f, 0.f, 0.f};
      acc = __builtin_amdgcn_mfma_f32_16x16x32_bf16(A[ct][0], b0.h, acc, 0, 0, 0);
      acc = __builtin_amdgcn_mfma_f32_16x16x32_bf16(A[ct][1], b1.h, acc, 0, 0, 0);
      int r0 = c0 + ct * 16 + lgrp * 4;
      if (r0 + 3 < CT) {
        float4 o;
        o.x = acc[0] + vb + addv[ct][0];
        o.y = acc[1] + vb + addv[ct][1];
        o.z = acc[2] + vb + addv[ct][2];
        o.w = acc[3] + vb + addv[ct][3];
        *(float4*)(outb + r0) = o;
      } else {
        for (int i = 0; i < 4; i++)
          if (r0 + i < CT) outb[r0 + i] = acc[i] + vb + addv[ct][i];
      }
    }
  }
}

// ---------------------------------------------------------------------------
// K6: EXP-space edge tables (log2 inputs -> v_exp_f32), bf16 packed.
__global__ __launch_bounds__(256) void k_edge(
    const float* __restrict__ beta1, const int* __restrict__ lf_t,
    const int* __restrict__ rf_t, const float* __restrict__ Gl,
    const float* __restrict__ Gr, const float* __restrict__ split0,
    uint32_t* __restrict__ elB, uint32_t* __restrict__ erB) {
  int sb = blockIdx.x;
  const float* brow = beta1 + (size_t)sb * CT;
  size_t ob = (size_t)sb * 720;
  for (int wd = threadIdx.x; wd < 720; wd += 256) {
    int res = wd / 20, p = wd - res * 20;
    float s0 = split0[res];
    int a0 = 2 * p, a1 = 2 * p + 1;
    uint32_t l0 = 0, l1 = 0, r0 = 0, r1 = 0;
    if (a0 < 36) {
      int i0 = a0 * 36 + res;
      l0 = f2bf_bits(EXP2F(brow[lf_t[i0]] + Gr[i0] + s0));
      r0 = f2bf_bits(EXP2F(brow[rf_t[i0]] + Gl[i0] + s0));
    }
    if (a1 < 36) {
      int i1 = a1 * 36 + res;
      l1 = f2bf_bits(EXP2F(brow[lf_t[i1]] + Gr[i1] + s0));
      r1 = f2bf_bits(EXP2F(brow[rf_t[i1]] + Gl[i1] + s0));
    }
    elB[ob + wd] = l0 | (l1 << 16);
    erB[ob + wd] = r0 | (r1 << 16);
  }
}

// ---------------------------------------------------------------------------
// K7: CKY inside pass, EXP(base-2)-space, bf16 edge tables. R6 skeleton
// (4x reproduced) + R12 mid-batching + R13 guarded atomicMax + raw v_exp.
// NO register caching in phase 2 (spills: R7/R10).
__global__ __launch_bounds__(1024, 4) void k_cky(
    const float* __restrict__ beta1, const uint32_t* __restrict__ elB,
    const uint32_t* __restrict__ erB, const float* __restrict__ Gl,
    const float* __restrict__ Gr, const float* __restrict__ split0,
    const float* __restrict__ root36, float* __restrict__ out) {
  __shared__ __align__(16) float D[19008];
  __shared__ float Mt[528];
  __shared__ __align__(16) float PA[1280], PB[1280];      // stride 40, padded
  __shared__ __align__(16) float Ec1lT[512], Ec1rT[512];  // [s][res][a]
  __shared__ __align__(16) float eGlT[16], eGrT[16];      // [res][a]
  __shared__ unsigned int candb[2][33];
  __shared__ float MIDacc[128];

  int b = blockIdx.x, tid = threadIdx.x;

  if (tid < 66) candb[tid / 33][tid % 33] = 0u;
  if (tid < 32) Mt[tid] = 0.f;
  if (tid < 16) {
    int res = tid >> 2, a = tid & 3;
    float s0 = split0[res];
    eGlT[tid] = EXP2F(Gl[a * 36 + res] + s0);
    eGrT[tid] = EXP2F(Gr[a * 36 + res] + s0);
  }
  for (int i = tid; i < 1280; i += 1024) { PA[i] = 0.f; PB[i] = 0.f; }
  __syncthreads();
  for (int i = tid; i < 32 * 36; i += 1024) {
    int s = i / 36;
    float v = EXP2F(beta1[(size_t)(s * 32 + b) * CT + (i - s * 36)]);
    D[i] = v;
    unsigned int vb_ = __float_as_uint(v);
    if (vb_ > candb[1][s]) atomicMax(&candb[1][s], vb_);
  }
  __syncthreads();
  for (int i = tid; i < 512; i += 1024) {
    int s = i >> 4, rr = (i >> 2) & 3, a = i & 3;
    float d1 = D[s * 36 + a];
    Ec1lT[i] = d1 * eGlT[rr * 4 + a];
    Ec1rT[i] = d1 * eGrT[rr * 4 + a];
  }
  __syncthreads();

  for (int L = 2; L <= 32; L++) {
    int S = 33 - L;
    int offL  = 36 * (((L - 1) * (66 - L)) >> 1);
    int offP  = 36 * (((L - 2) * (67 - L)) >> 1);
    int offML = ((L - 1) * (66 - L)) >> 1;
    int offMP = ((L - 2) * (67 - L)) >> 1;
    int par = L & 1, parP = par ^ 1;

    // ---- phase A: scale prev level into PA/PB; zero candb[par], MIDacc
    if (tid < 33) candb[par][tid] = 0u;
    if (tid >= 64 && tid < 192) MIDacc[tid - 64] = 0.f;
    int totA = S * 36;
    for (int o = tid; o < totA; o += 1024) {
      int s = o / 36, j = o - s * 36;
      float MtA = Mt[offMP + s], MtB = Mt[offMP + s + 1];
      float cA = MtA + __log2f(fmaxf(__uint_as_float(candb[parP][s]), 1e-37f));
      float cB = MtB + __log2f(fmaxf(__uint_as_float(candb[parP][s + 1]), 1e-37f));
      float Mn = fmaxf(cA, cB);
      PA[s * 40 + j] = D[offP + s * 36 + j] * EXP2F(MtA - Mn);
      PB[s * 40 + j] = D[offP + (s + 1) * 36 + j] * EXP2F(MtB - Mn);
      if (j == 0) Mt[offML + s] = Mn;
    }
    __syncthreads();

    // ---- phase 2: mains + mids (4 k-splits per mid item)
    int tot = S * 36;
    int ngrp = (L >= 4) ? ((L - 3 + 3) >> 2) : 0;   // ceil((L-3)/4)
    int nmid = 4 * S * ngrp;
    int W = tot + nmid;
    for (int o = tid; o < W; o += 1024) {
      if (o < tot) {
        int s = o / 36, res = o - s * 36;
        const uint4* el4 = (const uint4*)(elB + (size_t)(s * 32 + b) * 720 + res * 20);
        const uint4* er4 = (const uint4*)(erB + (size_t)((s + L - 1) * 32 + b) * 720 + res * 20);
        const float4* pB4 = (const float4*)(PB + s * 40);
        const float4* pA4 = (const float4*)(PA + s * 40);
        float a0 = 0.f, a1 = 0.f, a2 = 0.f, a3 = 0.f;
#pragma unroll
        for (int q = 0; q < 5; q++) {
          uint4 u = el4[q];
          float4 p0 = pB4[2 * q], p1 = pB4[2 * q + 1];
          a0 = fmaf(bflo(u.x), p0.x, a0); a1 = fmaf(bfhi(u.x), p0.y, a1);
          a2 = fmaf(bflo(u.y), p0.z, a2); a3 = fmaf(bfhi(u.y), p0.w, a3);
          a0 = fmaf(bflo(u.z), p1.x, a0); a1 = fmaf(bfhi(u.z), p1.y, a1);
          a2 = fmaf(bflo(u.w), p1.z, a2); a3 = fmaf(bfhi(u.w), p1.w, a3);
          uint4 v = er4[q];
          float4 q0 = pA4[2 * q], q1 = pA4[2 * q + 1];
          a0 = fmaf(bflo(v.x), q0.x, a0); a1 = fmaf(bfhi(v.x), q0.y, a1);
          a2 = fmaf(bflo(v.y), q0.z, a2); a3 = fmaf(bfhi(v.y), q0.w, a3);
          a0 = fmaf(bflo(v.z), q1.x, a0); a1 = fmaf(bfhi(v.z), q1.y, a1);
          a2 = fmaf(bflo(v.w), q1.z, a2); a3 = fmaf(bfhi(v.w), q1.w, a3);
        }
        if (res < 4 && L >= 3) {
          const float4* ecl = (const float4*)(Ec1lT + s * 16 + res * 4);
          const float4* ecr = (const float4*)(Ec1rT + (s + L - 1) * 16 + res * 4);
          float4 e0 = ecl[0], pb = pB4[5 + res];
          float4 e1 = ecr[0], pa = pA4[1 + res];
          a0 = fmaf(e0.x, pb.x, a0); a1 = fmaf(e0.y, pb.y, a1);
          a2 = fmaf(e0.z, pb.z, a2); a3 = fmaf(e0.w, pb.w, a3);
          a0 = fmaf(e1.x, pa.x, a0); a1 = fmaf(e1.y, pa.y, a1);
          a2 = fmaf(e1.z, pa.z, a2); a3 = fmaf(e1.w, pa.w, a3);
        }
        float val = (a0 + a1) + (a2 + a3);
        D[offL + o] = val;
        unsigned int vb_ = __float_as_uint(val);
        if (vb_ > candb[par][s]) atomicMax(&candb[par][s], vb_);
      } else {
        int o2 = o - tot;
        int grp = o2 / (4 * S);
        int rem = o2 - grp * 4 * S;
        int s = rem >> 2, res = rem & 3;
        float4 egl = ((const float4*)eGlT)[res];
        float4 egr = ((const float4*)eGrT)[res];
        float Mn = Mt[offML + s];
        float mv = 0.f;
        int kbase = grp * 4 + 2;
#pragma unroll 1
        for (int kk = 0; kk < 4; kk++) {
          int k = kbase + kk;
          if (k > L - 2) break;
          int lk = L - k;
          int tk = ((k - 1) * (66 - k)) >> 1;
          int tl = ((lk - 1) * (66 - lk)) >> 1;
          const float4* Dk4 = (const float4*)(D + 36 * tk + s * 36);
          const float4* Dl4 = (const float4*)(D + 36 * tl + (s + k) * 36);
          float4 dk0 = Dk4[0], dkh = Dk4[1 + res];
          float4 dl0 = Dl4[0], dlh = Dl4[5 + res];
          float f = EXP2F(Mt[tk + s] + Mt[tl + s + k] - Mn);
          float sub = dk0.x * dlh.x * egl.x + dk0.y * dlh.y * egl.y
                    + dk0.z * dlh.z * egl.z + dk0.w * dlh.w * egl.w
                    + dl0.x * dkh.x * egr.x + dl0.y * dkh.y * egr.y
                    + dl0.z * dkh.z * egr.z + dl0.w * dkh.w * egr.w;
          mv = fmaf(f, sub, mv);
        }
        atomicAdd(&MIDacc[rem], mv);
      }
    }
    __syncthreads();

    // ---- phase 3: merge mids into D (res<4 columns)
    if (L >= 4) {
      for (int o = tid; o < 4 * S; o += 1024) {
        int s = o >> 2;
        float nv = D[offL + s * 36 + (o & 3)] + MIDacc[o];
        D[offL + s * 36 + (o & 3)] = nv;
        unsigned int vb_ = __float_as_uint(nv);
        if (vb_ > candb[par][s]) atomicMax(&candb[par][s], vb_);
      }
    }
    __syncthreads();
  }

  int wid = tid >> 6, lane = tid & 63;
  if (wid == 0) {
    int off32 = 36 * ((31 * 34) >> 1);
    float v = (lane < 36) ? D[off32 + lane] * EXP2F(root36[lane]) : 0.f;
#pragma unroll
    for (int w = 32; w > 0; w >>= 1) v += __shfl_xor(v, w);
    if (lane == 0) out[b] = -(Mt[527] + __log2f(v)) * LN2F;
  }
}

// ---------------------------------------------------------------------------
extern "C" void kernel_launch(void* const* d_in, const int* in_sizes, int n_in,
                              void* d_out, int out_size, void* d_ws, size_t ws_size,
                              hipStream_t stream) {
  const int*   x       = (const int*)d_in[0];
  const int*   lf_t    = (const int*)d_in[1];
  const int*   rf_t    = (const int*)d_in[2];
  const float* root_W  = (const float*)d_in[3];
  const float* root_b  = (const float*)d_in[4];
  const float* rule_W  = (const float*)d_in[5];
  const float* rule_b  = (const float*)d_in[6];
  const float* nt_emb  = (const float*)d_in[7];
  const float* sW1     = (const float*)d_in[8];
  const float* sb1     = (const float*)d_in[9];
  const float* r1W1    = (const float*)d_in[10];
  const float* r1b1    = (const float*)d_in[11];
  const float* r1W2    = (const float*)d_in[12];
  const float* r1b2    = (const float*)d_in[13];
  const float* r2W1    = (const float*)d_in[14];
  const float* r2b1    = (const float*)d_in[15];
  const float* r2W2    = (const float*)d_in[16];
  const float* r2b2    = (const float*)d_in[17];
  const float* sW2     = (const float*)d_in[18];
  const float* sb2     = (const float*)d_in[19];
  const float* vocab_W = (const float*)d_in[20];
  const float* vocab_b = (const float*)d_in[21];
  float* outp = (float*)d_out;

  float* ws = (float*)d_ws;
  float* split0 = ws;                         // 2596
  float* split1 = ws + 2596;                  // 2596
  float* Gl     = ws + 5192;                  // 1296
  float* Gr     = ws + 6488;                  // 1296
  float* root36 = ws + 7784;                  // 64
  float* lseacc = ws + 7848;                  // 2596 (pad to 2600)
  float* vbt    = ws + 10448;                 // 1024
  float* beta1  = ws + 11472;                 // 2658304 -> end 2669776
  uint32_t* elB = (uint32_t*)(ws + 2669776);  // 737280 -> end 3407056
  uint32_t* erB = (uint32_t*)(ws + 3407056);  // 737280 -> end 4144336
  // Wt overlays elB/erB region: consumed by k_lse_mfma BEFORE k_edge writes.
  uint4* Wt     = (uint4*)(ws + 2669776);     // 256000 uint4
  uint4* Bt     = (uint4*)(ws + 4144336);     // 8192 uint4 -> end 4177104

  k_front<<<1719, 256, 0, stream>>>(nt_emb, sW1, sb1, r1W1, r1b1, r1W2, r1b2,
                                    r2W1, r2b1, r2W2, r2b2, sW2, sb2,
                                    vocab_W, vocab_b, x,
                                    rule_W, rule_b, root_W, root_b,
                                    split0, split1, Wt, Bt, vbt, lseacc,
                                    Gl, Gr, root36);
  k_lse_mfma<<<dim3(25, 21), 256, 0, stream>>>(nt_emb, Wt, vocab_b, lseacc);
  k_beta1_mfma<<<dim3(41, 8), 256, 0, stream>>>(nt_emb, Bt, vbt, lseacc, split1, beta1);
  k_edge<<<1024, 256, 0, stream>>>(beta1, lf_t, rf_t, Gl, Gr, split0, elB, erB);
  k_cky<<<32, 1024, 0, stream>>>(beta1, elB, erB, Gl, Gr, split0, root36, outp);
}

// Round 15
// 185.421 us; speedup vs baseline: 1.0928x; 1.0088x over previous
//
#include <hip/hip_runtime.h>
#include <hip/hip_bf16.h>
#include <math.h>

#define CT 2596      // total functor count C
#define NF36 36
#define BB 32        // batch
#define NN 32        // seq len
#define VV 32000
#define DD 64
#define NEGF -1e9f
#define LOG2E 1.4426950408889634f
#define LN2F  0.6931471805599453f

// hardware v_exp_f32 is base-2: direct map, no libcall, no extra mul
#define EXP2F(x) __builtin_amdgcn_exp2f(x)

typedef __attribute__((ext_vector_type(8))) short bf16x8;
typedef __attribute__((ext_vector_type(4))) float f32x4;

// bf16 helpers
__device__ __forceinline__ uint32_t f2bf_bits(float x) {
  union { float f; uint32_t u; } v; v.f = x;
  return (v.u + 0x7FFFu + ((v.u >> 16) & 1u)) >> 16;   // RNE
}
__device__ __forceinline__ float bflo(uint32_t u) {
  union { uint32_t u; float f; } v; v.u = u << 16; return v.f;
}
__device__ __forceinline__ float bfhi(uint32_t u) {
  union { uint32_t u; float f; } v; v.u = u & 0xFFFF0000u; return v.f;
}

// ---------------------------------------------------------------------------
// K1: fused front. ALL log-domain outputs are in BASE-2 units (×LOG2E).
__global__ __launch_bounds__(256) void k_front(
    const float* __restrict__ nt_emb,
    const float* __restrict__ sW1, const float* __restrict__ sb1,
    const float* __restrict__ r1W1, const float* __restrict__ r1b1,
    const float* __restrict__ r1W2, const float* __restrict__ r1b2,
    const float* __restrict__ r2W1, const float* __restrict__ r2b1,
    const float* __restrict__ r2W2, const float* __restrict__ r2b2,
    const float* __restrict__ sW2, const float* __restrict__ sb2,
    const float* __restrict__ vocab_W, const float* __restrict__ vocab_b,
    const int* __restrict__ x,
    const float* __restrict__ rule_W, const float* __restrict__ rule_b,
    const float* __restrict__ root_W, const float* __restrict__ root_b,
    float* __restrict__ split0, float* __restrict__ split1,
    uint4* __restrict__ Wt, uint4* __restrict__ Bt,
    float* __restrict__ vbt, float* __restrict__ lseacc,
    float* __restrict__ Gl, float* __restrict__ Gr,
    float* __restrict__ root36) {
  int blk = blockIdx.x;
  int tid = threadIdx.x;
  if (blk < 649) {
    __shared__ float hs[4][64], ts[4][64];
    __shared__ float WS[4096];
    int rl = tid >> 6, j = tid & 63;
    int c = blk * 4 + rl;
#define STAGE_W(Wp) for (int q = tid; q < 1024; q += 256) ((float4*)WS)[q] = ((const float4*)(Wp))[q];
    ts[rl][j] = nt_emb[(size_t)c * 64 + j];
    STAGE_W(sW1);
    __syncthreads();
    float a = sb1[j];
#pragma unroll 16
    for (int i = 0; i < 64; i++) a += ts[rl][i] * WS[i * 64 + j];
    __syncthreads();
    hs[rl][j] = a;
    STAGE_W(r1W1);
    __syncthreads();
    float u = r1b1[j];
#pragma unroll 16
    for (int i = 0; i < 64; i++) u += hs[rl][i] * WS[i * 64 + j];
    u = fmaxf(u, 0.f);
    __syncthreads();
    ts[rl][j] = u;
    STAGE_W(r1W2);
    __syncthreads();
    float w = r1b2[j];
#pragma unroll 16
    for (int i = 0; i < 64; i++) w += ts[rl][i] * WS[i * 64 + j];
    w = fmaxf(w, 0.f) + hs[rl][j];
    __syncthreads();
    hs[rl][j] = w;
    STAGE_W(r2W1);
    __syncthreads();
    u = r2b1[j];
#pragma unroll 16
    for (int i = 0; i < 64; i++) u += hs[rl][i] * WS[i * 64 + j];
    u = fmaxf(u, 0.f);
    __syncthreads();
    ts[rl][j] = u;
    STAGE_W(r2W2);
    __syncthreads();
    w = r2b2[j];
#pragma unroll 16
    for (int i = 0; i < 64; i++) w += ts[rl][i] * WS[i * 64 + j];
    w = fmaxf(w, 0.f) + hs[rl][j];
    __syncthreads();
    hs[rl][j] = w;
    __syncthreads();
    if (j < 2) {
      float o = sb2[j];
      for (int i = 0; i < 64; i++) o += hs[rl][i] * sW2[i * 2 + j];
      ts[rl][j] = o;
    }
    __syncthreads();
    if (j < 2) {
      float o0 = ts[rl][0], o1 = ts[rl][1];
      float mx = fmaxf(o0, o1);
      float l = mx + __logf(__expf(o0 - mx) + __expf(o1 - mx));
      if (j == 0) split0[c] = (o0 - l) * LOG2E;
      else        split1[c] = (o1 - l) * LOG2E;
    }
#undef STAGE_W
  } else if (blk < 1649) {
    int g = (blk - 649) * 256 + tid;
    int l = g & 63, f = (g >> 6) & 1, vt = g >> 7;
    int v = vt * 16 + (l & 15);
    int kb = f * 32 + 8 * (l >> 4);
    uint32_t d[4];
#pragma unroll
    for (int p = 0; p < 4; p++) {
      float a = vocab_W[(size_t)(kb + 2 * p) * VV + v];
      float b = vocab_W[(size_t)(kb + 2 * p + 1) * VV + v];
      d[p] = f2bf_bits(a) | (f2bf_bits(b) << 16);
    }
    uint4 o; o.x = d[0]; o.y = d[1]; o.z = d[2]; o.w = d[3];
    Wt[g] = o;
  } else if (blk < 1681) {
    int g = (blk - 1649) * 256 + tid;   // < 8192
    int l = g & 63, kf = (g >> 6) & 1, t = g >> 7;
    int j = t * 16 + (l & 15);
    int tok = x[j];
    int kb = kf * 32 + 8 * (l >> 4);
    uint32_t d[4];
#pragma unroll
    for (int p = 0; p < 4; p++) {
      float a = vocab_W[(size_t)(kb + 2 * p) * VV + tok];
      float b = vocab_W[(size_t)(kb + 2 * p + 1) * VV + tok];
      d[p] = f2bf_bits(a) | (f2bf_bits(b) << 16);
    }
    uint4 o; o.x = d[0]; o.y = d[1]; o.z = d[2]; o.w = d[3];
    Bt[g] = o;
    if (g < 1024) vbt[g] = vocab_b[x[g]] * LOG2E;
  } else if (blk == 1681) {
    for (int i = tid; i < CT; i += 256) lseacc[i] = 0.f;
  } else if (blk < 1718) {
    int res = blk - 1682;
    __shared__ float red[8];
    float v = (tid < 72) ? rule_W[res * 72 + tid] + rule_b[tid] : -1e30f;
    float m = v;
#pragma unroll
    for (int w = 32; w > 0; w >>= 1) m = fmaxf(m, __shfl_xor(m, w));
    if ((tid & 63) == 0) red[tid >> 6] = m;
    __syncthreads();
    m = fmaxf(fmaxf(red[0], red[1]), fmaxf(red[2], red[3]));
    float e = (tid < 72) ? __expf(v - m) : 0.f;
#pragma unroll
    for (int w = 32; w > 0; w >>= 1) e += __shfl_xor(e, w);
    if ((tid & 63) == 0) red[4 + (tid >> 6)] = e;
    __syncthreads();
    float l = m + __logf(red[4] + red[5] + red[6] + red[7]);
    if (tid < 36) {
      Gl[tid * 36 + res] = (rule_W[res * 72 + tid] + rule_b[tid] - l) * LOG2E;
      Gr[tid * 36 + res] = (rule_W[res * 72 + 36 + tid] + rule_b[36 + tid] - l) * LOG2E;
    }
  } else {
    __shared__ float lse4s;
    if (tid == 0) {
      float mx = -1e30f;
      for (int i = 0; i < 4; i++) mx = fmaxf(mx, root_W[i] + root_b[i]);
      float ss = 0.f;
      for (int i = 0; i < 4; i++) ss += __expf(root_W[i] + root_b[i] - mx);
      lse4s = mx + __logf(ss);
    }
    __syncthreads();
    if (tid < 36)
      root36[tid] = (((tid < 4) ? 0.f : NEGF) + root_W[tid] + root_b[tid] - lse4s) * LOG2E;
  }
}

// ---------------------------------------------------------------------------
// K4: MFMA GEMM + fused exp-sum over V. acc in log2 units -> raw v_exp_f32.
__global__ __launch_bounds__(256) void k_lse_mfma(
    const float* __restrict__ nt_emb, const uint4* __restrict__ Wt,
    const float* __restrict__ vocab_b, float* __restrict__ lseacc) {
  int tid = threadIdx.x;
  int w = tid >> 6, l = tid & 63;
  int c0 = blockIdx.y * 128;
  int lrow = l & 15, lgrp = l >> 4;

  bf16x8 A[8][2];
#pragma unroll
  for (int ct = 0; ct < 8; ct++) {
    int row = c0 + ct * 16 + lrow;
#pragma unroll
    for (int kf = 0; kf < 2; kf++) {
      bf16x8 fr;
      if (row < CT) {
        const float4* src = (const float4*)(nt_emb + (size_t)row * 64 + kf * 32 + lgrp * 8);
        float4 s0 = src[0], s1 = src[1];
        fr[0] = (short)f2bf_bits(s0.x * LOG2E); fr[1] = (short)f2bf_bits(s0.y * LOG2E);
        fr[2] = (short)f2bf_bits(s0.z * LOG2E); fr[3] = (short)f2bf_bits(s0.w * LOG2E);
        fr[4] = (short)f2bf_bits(s1.x * LOG2E); fr[5] = (short)f2bf_bits(s1.y * LOG2E);
        fr[6] = (short)f2bf_bits(s1.z * LOG2E); fr[7] = (short)f2bf_bits(s1.w * LOG2E);
      } else {
#pragma unroll
        for (int e = 0; e < 8; e++) fr[e] = 0;
      }
      A[ct][kf] = fr;
    }
  }

  float sums[8][4];
#pragma unroll
  for (int ct = 0; ct < 8; ct++)
#pragma unroll
    for (int i = 0; i < 4; i++) sums[ct][i] = 0.f;

  int t0 = blockIdx.x * 80;
  for (int t = t0 + w; t < t0 + 80; t += 4) {
    union { uint4 u; bf16x8 h; } b0, b1;
    b0.u = Wt[(size_t)(t * 2) * 64 + l];
    b1.u = Wt[(size_t)(t * 2 + 1) * 64 + l];
    float vb = vocab_b[t * 16 + lrow] * LOG2E;
#pragma unroll
    for (int ct = 0; ct < 8; ct++) {
      f32x4 acc = {0.f, 0.f, 0.f, 0.f};
      acc = __builtin_amdgcn_mfma_f32_16x16x32_bf16(A[ct][0], b0.h, acc, 0, 0, 0);
      acc = __builtin_amdgcn_mfma_f32_16x16x32_bf16(A[ct][1], b1.h, acc, 0, 0, 0);
#pragma unroll
      for (int i = 0; i < 4; i++) sums[ct][i] += EXP2F(acc[i] + vb);
    }
  }

#pragma unroll
  for (int ct = 0; ct < 8; ct++)
#pragma unroll
    for (int i = 0; i < 4; i++) {
      float v = sums[ct][i];
      v += __shfl_xor(v, 1);
      v += __shfl_xor(v, 2);
      v += __shfl_xor(v, 4);
      v += __shfl_xor(v, 8);
      sums[ct][i] = v;
    }
  if (lrow == 0) {
#pragma unroll
    for (int ct = 0; ct < 8; ct++)
#pragma unroll
      for (int i = 0; i < 4; i++) {
        int row = c0 + ct * 16 + lgrp * 4 + i;
        if (row < CT) atomicAdd(&lseacc[row], sums[ct][i]);
      }
  }
}

// ---------------------------------------------------------------------------
// K5: beta1 via MFMA (log2 units).
__global__ __launch_bounds__(256) void k_beta1_mfma(
    const float* __restrict__ nt_emb, const uint4* __restrict__ Bt,
    const float* __restrict__ vbt, const float* __restrict__ lseacc,
    const float* __restrict__ split1, float* __restrict__ beta1) {
  int tid = threadIdx.x;
  int w = tid >> 6, l = tid & 63;
  int c0 = blockIdx.x * 64;
  int lrow = l & 15, lgrp = l >> 4;
  __shared__ float addS[64];
  if (tid < 64) {
    int row = c0 + tid;
    addS[tid] = (row < CT) ? (split1[row] - __log2f(lseacc[row])) : 0.f;
  }

  bf16x8 A[4][2];
#pragma unroll
  for (int ct = 0; ct < 4; ct++) {
    int row = c0 + ct * 16 + lrow;
#pragma unroll
    for (int kf = 0; kf < 2; kf++) {
      bf16x8 fr;
      if (row < CT) {
        const float4* src = (const float4*)(nt_emb + (size_t)row * 64 + kf * 32 + lgrp * 8);
        float4 s0 = src[0], s1 = src[1];
        fr[0] = (short)f2bf_bits(s0.x * LOG2E); fr[1] = (short)f2bf_bits(s0.y * LOG2E);
        fr[2] = (short)f2bf_bits(s0.z * LOG2E); fr[3] = (short)f2bf_bits(s0.w * LOG2E);
        fr[4] = (short)f2bf_bits(s1.x * LOG2E); fr[5] = (short)f2bf_bits(s1.y * LOG2E);
        fr[6] = (short)f2bf_bits(s1.z * LOG2E); fr[7] = (short)f2bf_bits(s1.w * LOG2E);
      } else {
#pragma unroll
        for (int e = 0; e < 8; e++) fr[e] = 0;
      }
      A[ct][kf] = fr;
    }
  }
  __syncthreads();
  float addv[4][4];
#pragma unroll
  for (int ct = 0; ct < 4; ct++)
#pragma unroll
    for (int i = 0; i < 4; i++) addv[ct][i] = addS[ct * 16 + lgrp * 4 + i];

  int t0 = blockIdx.y * 8;
  for (int t = t0 + w; t < t0 + 8; t += 4) {
    union { uint4 u; bf16x8 h; } b0, b1;
    b0.u = Bt[t * 128 + l];
    b1.u = Bt[t * 128 + 64 + l];
    int j = t * 16 + lrow;
    float vb = vbt[j];
    int jc = (j & 31) * 32 + (j >> 5);
    float* outb = beta1 + (size_t)jc * CT;
#pragma unroll
    for (int ct = 0; ct < 4; ct++) {
      f32x4 acc = {0.f, 0.f, 0.f, 0.f};
      acc = __builtin_amdgcn_mfma_f32_16x16x32_bf16(A[ct][0], b0.h, acc, 0, 0, 0);
      acc = __builtin_amdgcn_mfma_f32_16x16x32_bf16(A[ct][1], b1.h, acc, 0, 0, 0);
      int r0 = c0 + ct * 16 + lgrp * 4;
      if (r0 + 3 < CT) {
        float4 o;
        o.x = acc[0] + vb + addv[ct][0];
        o.y = acc[1] + vb + addv[ct][1];
        o.z = acc[2] + vb + addv[ct][2];
        o.w = acc[3] + vb + addv[ct][3];
        *(float4*)(outb + r0) = o;
      } else {
        for (int i = 0; i < 4; i++)
          if (r0 + i < CT) outb[r0 + i] = acc[i] + vb + addv[ct][i];
      }
    }
  }
}

// ---------------------------------------------------------------------------
// K6: EXP-space edge tables (log2 inputs -> v_exp_f32), bf16 packed.
__global__ __launch_bounds__(256) void k_edge(
    const float* __restrict__ beta1, const int* __restrict__ lf_t,
    const int* __restrict__ rf_t, const float* __restrict__ Gl,
    const float* __restrict__ Gr, const float* __restrict__ split0,
    uint32_t* __restrict__ elB, uint32_t* __restrict__ erB) {
  int sb = blockIdx.x;
  const float* brow = beta1 + (size_t)sb * CT;
  size_t ob = (size_t)sb * 720;
  for (int wd = threadIdx.x; wd < 720; wd += 256) {
    int res = wd / 20, p = wd - res * 20;
    float s0 = split0[res];
    int a0 = 2 * p, a1 = 2 * p + 1;
    uint32_t l0 = 0, l1 = 0, r0 = 0, r1 = 0;
    if (a0 < 36) {
      int i0 = a0 * 36 + res;
      l0 = f2bf_bits(EXP2F(brow[lf_t[i0]] + Gr[i0] + s0));
      r0 = f2bf_bits(EXP2F(brow[rf_t[i0]] + Gl[i0] + s0));
    }
    if (a1 < 36) {
      int i1 = a1 * 36 + res;
      l1 = f2bf_bits(EXP2F(brow[lf_t[i1]] + Gr[i1] + s0));
      r1 = f2bf_bits(EXP2F(brow[rf_t[i1]] + Gl[i1] + s0));
    }
    elB[ob + wd] = l0 | (l1 << 16);
    erB[ob + wd] = r0 | (r1 << 16);
  }
}

// ---------------------------------------------------------------------------
// K7: CKY inside pass, EXP(base-2)-space, bf16 edge tables. R6 skeleton
// (4x reproduced) + R12 mid-batching + guarded atomicMax + raw v_exp.
// NEW: hot edge rows cached in LDS (el s<12, er s'>=20; 69KB of the 66KB
// previously-idle LDS) — LDS reads replace ~55% of the per-level L2/L3
// edge traffic. NO new register state (spill-proven danger, R7/R10).
__global__ __launch_bounds__(1024, 4) void k_cky(
    const float* __restrict__ beta1, const uint32_t* __restrict__ elB,
    const uint32_t* __restrict__ erB, const float* __restrict__ Gl,
    const float* __restrict__ Gr, const float* __restrict__ split0,
    const float* __restrict__ root36, float* __restrict__ out) {
  __shared__ __align__(16) float D[19008];
  __shared__ float Mt[528];
  __shared__ __align__(16) float PA[1280], PB[1280];      // stride 40, padded
  __shared__ __align__(16) float Ec1lT[512], Ec1rT[512];  // [s][res][a]
  __shared__ __align__(16) float eGlT[16], eGrT[16];      // [res][a]
  __shared__ unsigned int candb[2][33];
  __shared__ float MIDacc[128];
  __shared__ uint4 elC[2160];   // el rows s in [0,12): [s][res][5]
  __shared__ uint4 erC[2160];   // er rows s' in [20,32): [s'-20][res][5]

  int b = blockIdx.x, tid = threadIdx.x;

  // populate hot edge caches (layout matches global: res-major within s)
  {
    const uint4* elG = (const uint4*)elB;
    const uint4* erG = (const uint4*)erB;
    for (int i = tid; i < 2160; i += 1024) {
      int s = i / 180, rem = i - s * 180;
      elC[i] = elG[(size_t)(s * 32 + b) * 180 + rem];
      erC[i] = erG[(size_t)((s + 20) * 32 + b) * 180 + rem];
    }
  }

  if (tid < 66) candb[tid / 33][tid % 33] = 0u;
  if (tid < 32) Mt[tid] = 0.f;
  if (tid < 16) {
    int res = tid >> 2, a = tid & 3;
    float s0 = split0[res];
    eGlT[tid] = EXP2F(Gl[a * 36 + res] + s0);
    eGrT[tid] = EXP2F(Gr[a * 36 + res] + s0);
  }
  for (int i = tid; i < 1280; i += 1024) { PA[i] = 0.f; PB[i] = 0.f; }
  __syncthreads();
  for (int i = tid; i < 32 * 36; i += 1024) {
    int s = i / 36;
    float v = EXP2F(beta1[(size_t)(s * 32 + b) * CT + (i - s * 36)]);
    D[i] = v;
    unsigned int vb_ = __float_as_uint(v);
    if (vb_ > candb[1][s]) atomicMax(&candb[1][s], vb_);
  }
  __syncthreads();
  for (int i = tid; i < 512; i += 1024) {
    int s = i >> 4, rr = (i >> 2) & 3, a = i & 3;
    float d1 = D[s * 36 + a];
    Ec1lT[i] = d1 * eGlT[rr * 4 + a];
    Ec1rT[i] = d1 * eGrT[rr * 4 + a];
  }
  __syncthreads();

  for (int L = 2; L <= 32; L++) {
    int S = 33 - L;
    int offL  = 36 * (((L - 1) * (66 - L)) >> 1);
    int offP  = 36 * (((L - 2) * (67 - L)) >> 1);
    int offML = ((L - 1) * (66 - L)) >> 1;
    int offMP = ((L - 2) * (67 - L)) >> 1;
    int par = L & 1, parP = par ^ 1;

    // ---- phase A: scale prev level into PA/PB; zero candb[par], MIDacc
    if (tid < 33) candb[par][tid] = 0u;
    if (tid >= 64 && tid < 192) MIDacc[tid - 64] = 0.f;
    int totA = S * 36;
    for (int o = tid; o < totA; o += 1024) {
      int s = o / 36, j = o - s * 36;
      float MtA = Mt[offMP + s], MtB = Mt[offMP + s + 1];
      float cA = MtA + __log2f(fmaxf(__uint_as_float(candb[parP][s]), 1e-37f));
      float cB = MtB + __log2f(fmaxf(__uint_as_float(candb[parP][s + 1]), 1e-37f));
      float Mn = fmaxf(cA, cB);
      PA[s * 40 + j] = D[offP + s * 36 + j] * EXP2F(MtA - Mn);
      PB[s * 40 + j] = D[offP + (s + 1) * 36 + j] * EXP2F(MtB - Mn);
      if (j == 0) Mt[offML + s] = Mn;
    }
    __syncthreads();

    // ---- phase 2: mains + mids (4 k-splits per mid item)
    int tot = S * 36;
    int ngrp = (L >= 4) ? ((L - 3 + 3) >> 2) : 0;   // ceil((L-3)/4)
    int nmid = 4 * S * ngrp;
    int W = tot + nmid;
    for (int o = tid; o < W; o += 1024) {
      if (o < tot) {
        int s = o / 36, res = o - s * 36;
        int sr = s + L - 1;
        const float4* pB4 = (const float4*)(PB + s * 40);
        const float4* pA4 = (const float4*)(PA + s * 40);
        float a0 = 0.f, a1 = 0.f, a2 = 0.f, a3 = 0.f;
        // ---- el half (feeds pB4): LDS cache for s<12, else global
#define EL_BODY(EL4)                                                        \
  _Pragma("unroll")                                                         \
  for (int q = 0; q < 5; q++) {                                             \
    uint4 u = (EL4)[q];                                                     \
    float4 p0 = pB4[2 * q], p1 = pB4[2 * q + 1];                            \
    a0 = fmaf(bflo(u.x), p0.x, a0); a1 = fmaf(bfhi(u.x), p0.y, a1);         \
    a2 = fmaf(bflo(u.y), p0.z, a2); a3 = fmaf(bfhi(u.y), p0.w, a3);         \
    a0 = fmaf(bflo(u.z), p1.x, a0); a1 = fmaf(bfhi(u.z), p1.y, a1);         \
    a2 = fmaf(bflo(u.w), p1.z, a2); a3 = fmaf(bfhi(u.w), p1.w, a3);         \
  }
#define ER_BODY(ER4)                                                        \
  _Pragma("unroll")                                                         \
  for (int q = 0; q < 5; q++) {                                             \
    uint4 v = (ER4)[q];                                                     \
    float4 q0 = pA4[2 * q], q1 = pA4[2 * q + 1];                            \
    a0 = fmaf(bflo(v.x), q0.x, a0); a1 = fmaf(bfhi(v.x), q0.y, a1);         \
    a2 = fmaf(bflo(v.y), q0.z, a2); a3 = fmaf(bfhi(v.y), q0.w, a3);         \
    a0 = fmaf(bflo(v.z), q1.x, a0); a1 = fmaf(bfhi(v.z), q1.y, a1);         \
    a2 = fmaf(bflo(v.w), q1.z, a2); a3 = fmaf(bfhi(v.w), q1.w, a3);         \
  }
        if (s < 12) {
          const uint4* el4 = elC + (s * 180 + res * 5);
          EL_BODY(el4)
        } else {
          const uint4* el4 = (const uint4*)elB + ((size_t)(s * 32 + b) * 180 + res * 5);
          EL_BODY(el4)
        }
        // ---- er half (feeds pA4): LDS cache for sr>=20, else global
        if (sr >= 20) {
          const uint4* er4 = erC + ((sr - 20) * 180 + res * 5);
          ER_BODY(er4)
        } else {
          const uint4* er4 = (const uint4*)erB + ((size_t)(sr * 32 + b) * 180 + res * 5);
          ER_BODY(er4)
        }
#undef EL_BODY
#undef ER_BODY
        if (res < 4 && L >= 3) {
          const float4* ecl = (const float4*)(Ec1lT + s * 16 + res * 4);
          const float4* ecr = (const float4*)(Ec1rT + sr * 16 + res * 4);
          float4 e0 = ecl[0], pb = pB4[5 + res];
          float4 e1 = ecr[0], pa = pA4[1 + res];
          a0 = fmaf(e0.x, pb.x, a0); a1 = fmaf(e0.y, pb.y, a1);
          a2 = fmaf(e0.z, pb.z, a2); a3 = fmaf(e0.w, pb.w, a3);
          a0 = fmaf(e1.x, pa.x, a0); a1 = fmaf(e1.y, pa.y, a1);
          a2 = fmaf(e1.z, pa.z, a2); a3 = fmaf(e1.w, pa.w, a3);
        }
        float val = (a0 + a1) + (a2 + a3);
        D[offL + o] = val;
        unsigned int vb_ = __float_as_uint(val);
        if (vb_ > candb[par][s]) atomicMax(&candb[par][s], vb_);
      } else {
        int o2 = o - tot;
        int grp = o2 / (4 * S);
        int rem = o2 - grp * 4 * S;
        int s = rem >> 2, res = rem & 3;
        float4 egl = ((const float4*)eGlT)[res];
        float4 egr = ((const float4*)eGrT)[res];
        float Mn = Mt[offML + s];
        float mv = 0.f;
        int kbase = grp * 4 + 2;
#pragma unroll 1
        for (int kk = 0; kk < 4; kk++) {
          int k = kbase + kk;
          if (k > L - 2) break;
          int lk = L - k;
          int tk = ((k - 1) * (66 - k)) >> 1;
          int tl = ((lk - 1) * (66 - lk)) >> 1;
          const float4* Dk4 = (const float4*)(D + 36 * tk + s * 36);
          const float4* Dl4 = (const float4*)(D + 36 * tl + (s + k) * 36);
          float4 dk0 = Dk4[0], dkh = Dk4[1 + res];
          float4 dl0 = Dl4[0], dlh = Dl4[5 + res];
          float f = EXP2F(Mt[tk + s] + Mt[tl + s + k] - Mn);
          float sub = dk0.x * dlh.x * egl.x + dk0.y * dlh.y * egl.y
                    + dk0.z * dlh.z * egl.z + dk0.w * dlh.w * egl.w
                    + dl0.x * dkh.x * egr.x + dl0.y * dkh.y * egr.y
                    + dl0.z * dkh.z * egr.z + dl0.w * dkh.w * egr.w;
          mv = fmaf(f, sub, mv);
        }
        atomicAdd(&MIDacc[rem], mv);
      }
    }
    __syncthreads();

    // ---- phase 3: merge mids into D (res<4 columns)
    if (L >= 4) {
      for (int o = tid; o < 4 * S; o += 1024) {
        int s = o >> 2;
        float nv = D[offL + s * 36 + (o & 3)] + MIDacc[o];
        D[offL + s * 36 + (o & 3)] = nv;
        unsigned int vb_ = __float_as_uint(nv);
        if (vb_ > candb[par][s]) atomicMax(&candb[par][s], vb_);
      }
    }
    __syncthreads();
  }

  int wid = tid >> 6, lane = tid & 63;
  if (wid == 0) {
    int off32 = 36 * ((31 * 34) >> 1);
    float v = (lane < 36) ? D[off32 + lane] * EXP2F(root36[lane]) : 0.f;
#pragma unroll
    for (int w = 32; w > 0; w >>= 1) v += __shfl_xor(v, w);
    if (lane == 0) out[b] = -(Mt[527] + __log2f(v)) * LN2F;
  }
}

// ---------------------------------------------------------------------------
extern "C" void kernel_launch(void* const* d_in, const int* in_sizes, int n_in,
                              void* d_out, int out_size, void* d_ws, size_t ws_size,
                              hipStream_t stream) {
  const int*   x       = (const int*)d_in[0];
  const int*   lf_t    = (const int*)d_in[1];
  const int*   rf_t    = (const int*)d_in[2];
  const float* root_W  = (const float*)d_in[3];
  const float* root_b  = (const float*)d_in[4];
  const float* rule_W  = (const float*)d_in[5];
  const float* rule_b  = (const float*)d_in[6];
  const float* nt_emb  = (const float*)d_in[7];
  const float* sW1     = (const float*)d_in[8];
  const float* sb1     = (const float*)d_in[9];
  const float* r1W1    = (const float*)d_in[10];
  const float* r1b1    = (const float*)d_in[11];
  const float* r1W2    = (const float*)d_in[12];
  const float* r1b2    = (const float*)d_in[13];
  const float* r2W1    = (const float*)d_in[14];
  const float* r2b1    = (const float*)d_in[15];
  const float* r2W2    = (const float*)d_in[16];
  const float* r2b2    = (const float*)d_in[17];
  const float* sW2     = (const float*)d_in[18];
  const float* sb2     = (const float*)d_in[19];
  const float* vocab_W = (const float*)d_in[20];
  const float* vocab_b = (const float*)d_in[21];
  float* outp = (float*)d_out;

  float* ws = (float*)d_ws;
  float* split0 = ws;                         // 2596
  float* split1 = ws + 2596;                  // 2596
  float* Gl     = ws + 5192;                  // 1296
  float* Gr     = ws + 6488;                  // 1296
  float* root36 = ws + 7784;                  // 64
  float* lseacc = ws + 7848;                  // 2596 (pad to 2600)
  float* vbt    = ws + 10448;                 // 1024
  float* beta1  = ws + 11472;                 // 2658304 -> end 2669776
  uint32_t* elB = (uint32_t*)(ws + 2669776);  // 737280 -> end 3407056
  uint32_t* erB = (uint32_t*)(ws + 3407056);  // 737280 -> end 4144336
  // Wt overlays elB/erB region: consumed by k_lse_mfma BEFORE k_edge writes.
  uint4* Wt     = (uint4*)(ws + 2669776);     // 256000 uint4
  uint4* Bt     = (uint4*)(ws + 4144336);     // 8192 uint4 -> end 4177104

  k_front<<<1719, 256, 0, stream>>>(nt_emb, sW1, sb1, r1W1, r1b1, r1W2, r1b2,
                                    r2W1, r2b1, r2W2, r2b2, sW2, sb2,
                                    vocab_W, vocab_b, x,
                                    rule_W, rule_b, root_W, root_b,
                                    split0, split1, Wt, Bt, vbt, lseacc,
                                    Gl, Gr, root36);
  k_lse_mfma<<<dim3(25, 21), 256, 0, stream>>>(nt_emb, Wt, vocab_b, lseacc);
  k_beta1_mfma<<<dim3(41, 8), 256, 0, stream>>>(nt_emb, Bt, vbt, lseacc, split1, beta1);
  k_edge<<<1024, 256, 0, stream>>>(beta1, lf_t, rf_t, Gl, Gr, split0, elB, erB);
  k_cky<<<32, 1024, 0, stream>>>(beta1, elB, erB, Gl, Gr, split0, root36, outp);
}

// Round 16
// 184.105 us; speedup vs baseline: 1.1006x; 1.0071x over previous
//
#include <hip/hip_runtime.h>
#include <hip/hip_bf16.h>
#include <math.h>

#define CT 2596      // total functor count C
#define NF36 36
#define BB 32        // batch
#define NN 32        // seq len
#define VV 32000
#define DD 64
#define NEGF -1e9f
#define LOG2E 1.4426950408889634f
#define LN2F  0.6931471805599453f

// hardware v_exp_f32 is base-2: direct map, no libcall, no extra mul
#define EXP2F(x) __builtin_amdgcn_exp2f(x)

typedef __attribute__((ext_vector_type(8))) short bf16x8;
typedef __attribute__((ext_vector_type(4))) float f32x4;

// bf16 helpers
__device__ __forceinline__ uint32_t f2bf_bits(float x) {
  union { float f; uint32_t u; } v; v.f = x;
  return (v.u + 0x7FFFu + ((v.u >> 16) & 1u)) >> 16;   // RNE
}
__device__ __forceinline__ float bflo(uint32_t u) {
  union { uint32_t u; float f; } v; v.u = u << 16; return v.f;
}
__device__ __forceinline__ float bfhi(uint32_t u) {
  union { uint32_t u; float f; } v; v.u = u & 0xFFFF0000u; return v.f;
}

// ---------------------------------------------------------------------------
// K1: fused front. ALL log-domain outputs are in BASE-2 units (×LOG2E).
__global__ __launch_bounds__(256) void k_front(
    const float* __restrict__ nt_emb,
    const float* __restrict__ sW1, const float* __restrict__ sb1,
    const float* __restrict__ r1W1, const float* __restrict__ r1b1,
    const float* __restrict__ r1W2, const float* __restrict__ r1b2,
    const float* __restrict__ r2W1, const float* __restrict__ r2b1,
    const float* __restrict__ r2W2, const float* __restrict__ r2b2,
    const float* __restrict__ sW2, const float* __restrict__ sb2,
    const float* __restrict__ vocab_W, const float* __restrict__ vocab_b,
    const int* __restrict__ x,
    const float* __restrict__ rule_W, const float* __restrict__ rule_b,
    const float* __restrict__ root_W, const float* __restrict__ root_b,
    float* __restrict__ split0, float* __restrict__ split1,
    uint4* __restrict__ Wt, uint4* __restrict__ Bt,
    float* __restrict__ vbt, float* __restrict__ lseacc,
    float* __restrict__ Gl, float* __restrict__ Gr,
    float* __restrict__ root36) {
  int blk = blockIdx.x;
  int tid = threadIdx.x;
  if (blk < 649) {
    __shared__ float hs[4][64], ts[4][64];
    __shared__ float WS[4096];
    int rl = tid >> 6, j = tid & 63;
    int c = blk * 4 + rl;
#define STAGE_W(Wp) for (int q = tid; q < 1024; q += 256) ((float4*)WS)[q] = ((const float4*)(Wp))[q];
    ts[rl][j] = nt_emb[(size_t)c * 64 + j];
    STAGE_W(sW1);
    __syncthreads();
    float a = sb1[j];
#pragma unroll 16
    for (int i = 0; i < 64; i++) a += ts[rl][i] * WS[i * 64 + j];
    __syncthreads();
    hs[rl][j] = a;
    STAGE_W(r1W1);
    __syncthreads();
    float u = r1b1[j];
#pragma unroll 16
    for (int i = 0; i < 64; i++) u += hs[rl][i] * WS[i * 64 + j];
    u = fmaxf(u, 0.f);
    __syncthreads();
    ts[rl][j] = u;
    STAGE_W(r1W2);
    __syncthreads();
    float w = r1b2[j];
#pragma unroll 16
    for (int i = 0; i < 64; i++) w += ts[rl][i] * WS[i * 64 + j];
    w = fmaxf(w, 0.f) + hs[rl][j];
    __syncthreads();
    hs[rl][j] = w;
    STAGE_W(r2W1);
    __syncthreads();
    u = r2b1[j];
#pragma unroll 16
    for (int i = 0; i < 64; i++) u += hs[rl][i] * WS[i * 64 + j];
    u = fmaxf(u, 0.f);
    __syncthreads();
    ts[rl][j] = u;
    STAGE_W(r2W2);
    __syncthreads();
    w = r2b2[j];
#pragma unroll 16
    for (int i = 0; i < 64; i++) w += ts[rl][i] * WS[i * 64 + j];
    w = fmaxf(w, 0.f) + hs[rl][j];
    __syncthreads();
    hs[rl][j] = w;
    __syncthreads();
    if (j < 2) {
      float o = sb2[j];
      for (int i = 0; i < 64; i++) o += hs[rl][i] * sW2[i * 2 + j];
      ts[rl][j] = o;
    }
    __syncthreads();
    if (j < 2) {
      float o0 = ts[rl][0], o1 = ts[rl][1];
      float mx = fmaxf(o0, o1);
      float l = mx + __logf(__expf(o0 - mx) + __expf(o1 - mx));
      if (j == 0) split0[c] = (o0 - l) * LOG2E;
      else        split1[c] = (o1 - l) * LOG2E;
    }
#undef STAGE_W
  } else if (blk < 1649) {
    int g = (blk - 649) * 256 + tid;
    int l = g & 63, f = (g >> 6) & 1, vt = g >> 7;
    int v = vt * 16 + (l & 15);
    int kb = f * 32 + 8 * (l >> 4);
    uint32_t d[4];
#pragma unroll
    for (int p = 0; p < 4; p++) {
      float a = vocab_W[(size_t)(kb + 2 * p) * VV + v];
      float b = vocab_W[(size_t)(kb + 2 * p + 1) * VV + v];
      d[p] = f2bf_bits(a) | (f2bf_bits(b) << 16);
    }
    uint4 o; o.x = d[0]; o.y = d[1]; o.z = d[2]; o.w = d[3];
    Wt[g] = o;
  } else if (blk < 1681) {
    int g = (blk - 1649) * 256 + tid;   // < 8192
    int l = g & 63, kf = (g >> 6) & 1, t = g >> 7;
    int j = t * 16 + (l & 15);
    int tok = x[j];
    int kb = kf * 32 + 8 * (l >> 4);
    uint32_t d[4];
#pragma unroll
    for (int p = 0; p < 4; p++) {
      float a = vocab_W[(size_t)(kb + 2 * p) * VV + tok];
      float b = vocab_W[(size_t)(kb + 2 * p + 1) * VV + tok];
      d[p] = f2bf_bits(a) | (f2bf_bits(b) << 16);
    }
    uint4 o; o.x = d[0]; o.y = d[1]; o.z = d[2]; o.w = d[3];
    Bt[g] = o;
    if (g < 1024) vbt[g] = vocab_b[x[g]] * LOG2E;
  } else if (blk == 1681) {
    for (int i = tid; i < CT; i += 256) lseacc[i] = 0.f;
  } else if (blk < 1718) {
    int res = blk - 1682;
    __shared__ float red[8];
    float v = (tid < 72) ? rule_W[res * 72 + tid] + rule_b[tid] : -1e30f;
    float m = v;
#pragma unroll
    for (int w = 32; w > 0; w >>= 1) m = fmaxf(m, __shfl_xor(m, w));
    if ((tid & 63) == 0) red[tid >> 6] = m;
    __syncthreads();
    m = fmaxf(fmaxf(red[0], red[1]), fmaxf(red[2], red[3]));
    float e = (tid < 72) ? __expf(v - m) : 0.f;
#pragma unroll
    for (int w = 32; w > 0; w >>= 1) e += __shfl_xor(e, w);
    if ((tid & 63) == 0) red[4 + (tid >> 6)] = e;
    __syncthreads();
    float l = m + __logf(red[4] + red[5] + red[6] + red[7]);
    if (tid < 36) {
      Gl[tid * 36 + res] = (rule_W[res * 72 + tid] + rule_b[tid] - l) * LOG2E;
      Gr[tid * 36 + res] = (rule_W[res * 72 + 36 + tid] + rule_b[36 + tid] - l) * LOG2E;
    }
  } else {
    __shared__ float lse4s;
    if (tid == 0) {
      float mx = -1e30f;
      for (int i = 0; i < 4; i++) mx = fmaxf(mx, root_W[i] + root_b[i]);
      float ss = 0.f;
      for (int i = 0; i < 4; i++) ss += __expf(root_W[i] + root_b[i] - mx);
      lse4s = mx + __logf(ss);
    }
    __syncthreads();
    if (tid < 36)
      root36[tid] = (((tid < 4) ? 0.f : NEGF) + root_W[tid] + root_b[tid] - lse4s) * LOG2E;
  }
}

// ---------------------------------------------------------------------------
// K4: MFMA GEMM + fused exp-sum over V. acc in log2 units -> raw v_exp_f32.
__global__ __launch_bounds__(256) void k_lse_mfma(
    const float* __restrict__ nt_emb, const uint4* __restrict__ Wt,
    const float* __restrict__ vocab_b, float* __restrict__ lseacc) {
  int tid = threadIdx.x;
  int w = tid >> 6, l = tid & 63;
  int c0 = blockIdx.y * 128;
  int lrow = l & 15, lgrp = l >> 4;

  bf16x8 A[8][2];
#pragma unroll
  for (int ct = 0; ct < 8; ct++) {
    int row = c0 + ct * 16 + lrow;
#pragma unroll
    for (int kf = 0; kf < 2; kf++) {
      bf16x8 fr;
      if (row < CT) {
        const float4* src = (const float4*)(nt_emb + (size_t)row * 64 + kf * 32 + lgrp * 8);
        float4 s0 = src[0], s1 = src[1];
        fr[0] = (short)f2bf_bits(s0.x * LOG2E); fr[1] = (short)f2bf_bits(s0.y * LOG2E);
        fr[2] = (short)f2bf_bits(s0.z * LOG2E); fr[3] = (short)f2bf_bits(s0.w * LOG2E);
        fr[4] = (short)f2bf_bits(s1.x * LOG2E); fr[5] = (short)f2bf_bits(s1.y * LOG2E);
        fr[6] = (short)f2bf_bits(s1.z * LOG2E); fr[7] = (short)f2bf_bits(s1.w * LOG2E);
      } else {
#pragma unroll
        for (int e = 0; e < 8; e++) fr[e] = 0;
      }
      A[ct][kf] = fr;
    }
  }

  float sums[8][4];
#pragma unroll
  for (int ct = 0; ct < 8; ct++)
#pragma unroll
    for (int i = 0; i < 4; i++) sums[ct][i] = 0.f;

  int t0 = blockIdx.x * 80;
  for (int t = t0 + w; t < t0 + 80; t += 4) {
    union { uint4 u; bf16x8 h; } b0, b1;
    b0.u = Wt[(size_t)(t * 2) * 64 + l];
    b1.u = Wt[(size_t)(t * 2 + 1) * 64 + l];
    float vb = vocab_b[t * 16 + lrow] * LOG2E;
#pragma unroll
    for (int ct = 0; ct < 8; ct++) {
      f32x4 acc = {0.f, 0.f, 0.f, 0.f};
      acc = __builtin_amdgcn_mfma_f32_16x16x32_bf16(A[ct][0], b0.h, acc, 0, 0, 0);
      acc = __builtin_amdgcn_mfma_f32_16x16x32_bf16(A[ct][1], b1.h, acc, 0, 0, 0);
#pragma unroll
      for (int i = 0; i < 4; i++) sums[ct][i] += EXP2F(acc[i] + vb);
    }
  }

#pragma unroll
  for (int ct = 0; ct < 8; ct++)
#pragma unroll
    for (int i = 0; i < 4; i++) {
      float v = sums[ct][i];
      v += __shfl_xor(v, 1);
      v += __shfl_xor(v, 2);
      v += __shfl_xor(v, 4);
      v += __shfl_xor(v, 8);
      sums[ct][i] = v;
    }
  if (lrow == 0) {
#pragma unroll
    for (int ct = 0; ct < 8; ct++)
#pragma unroll
      for (int i = 0; i < 4; i++) {
        int row = c0 + ct * 16 + lgrp * 4 + i;
        if (row < CT) atomicAdd(&lseacc[row], sums[ct][i]);
      }
  }
}

// ---------------------------------------------------------------------------
// K5: beta1 via MFMA (log2 units).
__global__ __launch_bounds__(256) void k_beta1_mfma(
    const float* __restrict__ nt_emb, const uint4* __restrict__ Bt,
    const float* __restrict__ vbt, const float* __restrict__ lseacc,
    const float* __restrict__ split1, float* __restrict__ beta1) {
  int tid = threadIdx.x;
  int w = tid >> 6, l = tid & 63;
  int c0 = blockIdx.x * 64;
  int lrow = l & 15, lgrp = l >> 4;
  __shared__ float addS[64];
  if (tid < 64) {
    int row = c0 + tid;
    addS[tid] = (row < CT) ? (split1[row] - __log2f(lseacc[row])) : 0.f;
  }

  bf16x8 A[4][2];
#pragma unroll
  for (int ct = 0; ct < 4; ct++) {
    int row = c0 + ct * 16 + lrow;
#pragma unroll
    for (int kf = 0; kf < 2; kf++) {
      bf16x8 fr;
      if (row < CT) {
        const float4* src = (const float4*)(nt_emb + (size_t)row * 64 + kf * 32 + lgrp * 8);
        float4 s0 = src[0], s1 = src[1];
        fr[0] = (short)f2bf_bits(s0.x * LOG2E); fr[1] = (short)f2bf_bits(s0.y * LOG2E);
        fr[2] = (short)f2bf_bits(s0.z * LOG2E); fr[3] = (short)f2bf_bits(s0.w * LOG2E);
        fr[4] = (short)f2bf_bits(s1.x * LOG2E); fr[5] = (short)f2bf_bits(s1.y * LOG2E);
        fr[6] = (short)f2bf_bits(s1.z * LOG2E); fr[7] = (short)f2bf_bits(s1.w * LOG2E);
      } else {
#pragma unroll
        for (int e = 0; e < 8; e++) fr[e] = 0;
      }
      A[ct][kf] = fr;
    }
  }
  __syncthreads();
  float addv[4][4];
#pragma unroll
  for (int ct = 0; ct < 4; ct++)
#pragma unroll
    for (int i = 0; i < 4; i++) addv[ct][i] = addS[ct * 16 + lgrp * 4 + i];

  int t0 = blockIdx.y * 8;
  for (int t = t0 + w; t < t0 + 8; t += 4) {
    union { uint4 u; bf16x8 h; } b0, b1;
    b0.u = Bt[t * 128 + l];
    b1.u = Bt[t * 128 + 64 + l];
    int j = t * 16 + lrow;
    float vb = vbt[j];
    int jc = (j & 31) * 32 + (j >> 5);
    float* outb = beta1 + (size_t)jc * CT;
#pragma unroll
    for (int ct = 0; ct < 4; ct++) {
      f32x4 acc = {0.f, 0.f, 0.f, 0.f};
      acc = __builtin_amdgcn_mfma_f32_16x16x32_bf16(A[ct][0], b0.h, acc, 0, 0, 0);
      acc = __builtin_amdgcn_mfma_f32_16x16x32_bf16(A[ct][1], b1.h, acc, 0, 0, 0);
      int r0 = c0 + ct * 16 + lgrp * 4;
      if (r0 + 3 < CT) {
        float4 o;
        o.x = acc[0] + vb + addv[ct][0];
        o.y = acc[1] + vb + addv[ct][1];
        o.z = acc[2] + vb + addv[ct][2];
        o.w = acc[3] + vb + addv[ct][3];
        *(float4*)(outb + r0) = o;
      } else {
        for (int i = 0; i < 4; i++)
          if (r0 + i < CT) outb[r0 + i] = acc[i] + vb + addv[ct][i];
      }
    }
  }
}

// ---------------------------------------------------------------------------
// K6: EXP-space edge tables (log2 inputs -> v_exp_f32), bf16 packed.
__global__ __launch_bounds__(256) void k_edge(
    const float* __restrict__ beta1, const int* __restrict__ lf_t,
    const int* __restrict__ rf_t, const float* __restrict__ Gl,
    const float* __restrict__ Gr, const float* __restrict__ split0,
    uint32_t* __restrict__ elB, uint32_t* __restrict__ erB) {
  int sb = blockIdx.x;
  const float* brow = beta1 + (size_t)sb * CT;
  size_t ob = (size_t)sb * 720;
  for (int wd = threadIdx.x; wd < 720; wd += 256) {
    int res = wd / 20, p = wd - res * 20;
    float s0 = split0[res];
    int a0 = 2 * p, a1 = 2 * p + 1;
    uint32_t l0 = 0, l1 = 0, r0 = 0, r1 = 0;
    if (a0 < 36) {
      int i0 = a0 * 36 + res;
      l0 = f2bf_bits(EXP2F(brow[lf_t[i0]] + Gr[i0] + s0));
      r0 = f2bf_bits(EXP2F(brow[rf_t[i0]] + Gl[i0] + s0));
    }
    if (a1 < 36) {
      int i1 = a1 * 36 + res;
      l1 = f2bf_bits(EXP2F(brow[lf_t[i1]] + Gr[i1] + s0));
      r1 = f2bf_bits(EXP2F(brow[rf_t[i1]] + Gl[i1] + s0));
    }
    elB[ob + wd] = l0 | (l1 << 16);
    erB[ob + wd] = r0 | (r1 << 16);
  }
}

// ---------------------------------------------------------------------------
// K7: CKY inside pass, EXP(base-2)-space, bf16 edge tables.
// R6 skeleton + R12 mid-batching + guarded atomicMax + R15 LDS edge cache.
// NEW this round (R8's two clean pieces, isolated): slim phase A (per-s
// factors fAs/fBs computed by S threads; PA/PB deleted) + mains read D
// directly with SPLIT accumulators, scaled by fB/fA at the end. Phase 3 and
// candb semantics unchanged. D zero-initialized so row-tail over-reads
// (old PB padding) hit finite zeros (edge words there are 0).
__global__ __launch_bounds__(1024, 4) void k_cky(
    const float* __restrict__ beta1, const uint32_t* __restrict__ elB,
    const uint32_t* __restrict__ erB, const float* __restrict__ Gl,
    const float* __restrict__ Gr, const float* __restrict__ split0,
    const float* __restrict__ root36, float* __restrict__ out) {
  __shared__ __align__(16) float D[19008];
  __shared__ float Mt[528];
  __shared__ float fAs[32], fBs[32];
  __shared__ __align__(16) float Ec1lT[512], Ec1rT[512];  // [s][res][a]
  __shared__ __align__(16) float eGlT[16], eGrT[16];      // [res][a]
  __shared__ unsigned int candb[2][33];
  __shared__ float MIDacc[128];
  __shared__ uint4 elC[2160];   // el rows s in [0,12): [s][res][5]
  __shared__ uint4 erC[2160];   // er rows s' in [20,32): [s'-20][res][5]

  int b = blockIdx.x, tid = threadIdx.x;

  // zero D so padding over-reads are finite (0 x 0-edge = 0)
  for (int i = tid; i < 19008; i += 1024) D[i] = 0.f;

  // populate hot edge caches (layout matches global: res-major within s)
  {
    const uint4* elG = (const uint4*)elB;
    const uint4* erG = (const uint4*)erB;
    for (int i = tid; i < 2160; i += 1024) {
      int s = i / 180, rem = i - s * 180;
      elC[i] = elG[(size_t)(s * 32 + b) * 180 + rem];
      erC[i] = erG[(size_t)((s + 20) * 32 + b) * 180 + rem];
    }
  }

  if (tid < 66) candb[tid / 33][tid % 33] = 0u;
  if (tid < 32) Mt[tid] = 0.f;
  if (tid < 16) {
    int res = tid >> 2, a = tid & 3;
    float s0 = split0[res];
    eGlT[tid] = EXP2F(Gl[a * 36 + res] + s0);
    eGrT[tid] = EXP2F(Gr[a * 36 + res] + s0);
  }
  __syncthreads();
  for (int i = tid; i < 32 * 36; i += 1024) {
    int s = i / 36;
    float v = EXP2F(beta1[(size_t)(s * 32 + b) * CT + (i - s * 36)]);
    D[i] = v;
    unsigned int vb_ = __float_as_uint(v);
    if (vb_ > candb[1][s]) atomicMax(&candb[1][s], vb_);
  }
  __syncthreads();
  for (int i = tid; i < 512; i += 1024) {
    int s = i >> 4, rr = (i >> 2) & 3, a = i & 3;
    float d1 = D[s * 36 + a];
    Ec1lT[i] = d1 * eGlT[rr * 4 + a];
    Ec1rT[i] = d1 * eGrT[rr * 4 + a];
  }
  __syncthreads();

  for (int L = 2; L <= 32; L++) {
    int S = 33 - L;
    int offL  = 36 * (((L - 1) * (66 - L)) >> 1);
    int offP  = 36 * (((L - 2) * (67 - L)) >> 1);
    int offML = ((L - 1) * (66 - L)) >> 1;
    int offMP = ((L - 2) * (67 - L)) >> 1;
    int par = L & 1, parP = par ^ 1;

    // ---- phase A (slim): per-s factors; zero candb[par], MIDacc
    if (tid < 33) {
      candb[par][tid] = 0u;
    } else if (tid >= 64 && tid < 192) {
      MIDacc[tid - 64] = 0.f;
    } else if (tid >= 256 && tid < 256 + S) {
      int s = tid - 256;
      float MtA = Mt[offMP + s], MtB = Mt[offMP + s + 1];
      float cA = MtA + __log2f(fmaxf(__uint_as_float(candb[parP][s]), 1e-37f));
      float cB = MtB + __log2f(fmaxf(__uint_as_float(candb[parP][s + 1]), 1e-37f));
      float Mn = fmaxf(cA, cB);
      Mt[offML + s] = Mn;
      fAs[s] = EXP2F(MtA - Mn);
      fBs[s] = EXP2F(MtB - Mn);
    }
    __syncthreads();

    // ---- phase 2: mains (direct D reads, split accumulators) + mids
    int tot = S * 36;
    int ngrp = (L >= 4) ? ((L - 3 + 3) >> 2) : 0;   // ceil((L-3)/4)
    int nmid = 4 * S * ngrp;
    int W = tot + nmid;
    for (int o = tid; o < W; o += 1024) {
      if (o < tot) {
        int s = o / 36, res = o - s * 36;
        int sr = s + L - 1;
        const float4* dB4 = (const float4*)(D + offP + (s + 1) * 36);
        const float4* dA4 = (const float4*)(D + offP + s * 36);
        float b0 = 0.f, b1 = 0.f, b2 = 0.f, b3 = 0.f;   // el half (x fB)
        float c0 = 0.f, c1 = 0.f, c2 = 0.f, c3 = 0.f;   // er half (x fA)
#define EL_BODY(EL4)                                                        \
  _Pragma("unroll")                                                         \
  for (int q = 0; q < 5; q++) {                                             \
    uint4 u = (EL4)[q];                                                     \
    float4 p0 = dB4[2 * q], p1 = dB4[2 * q + 1];                            \
    b0 = fmaf(bflo(u.x), p0.x, b0); b1 = fmaf(bfhi(u.x), p0.y, b1);         \
    b2 = fmaf(bflo(u.y), p0.z, b2); b3 = fmaf(bfhi(u.y), p0.w, b3);         \
    b0 = fmaf(bflo(u.z), p1.x, b0); b1 = fmaf(bfhi(u.z), p1.y, b1);         \
    b2 = fmaf(bflo(u.w), p1.z, b2); b3 = fmaf(bfhi(u.w), p1.w, b3);         \
  }
#define ER_BODY(ER4)                                                        \
  _Pragma("unroll")                                                         \
  for (int q = 0; q < 5; q++) {                                             \
    uint4 v = (ER4)[q];                                                     \
    float4 q0 = dA4[2 * q], q1 = dA4[2 * q + 1];                            \
    c0 = fmaf(bflo(v.x), q0.x, c0); c1 = fmaf(bfhi(v.x), q0.y, c1);         \
    c2 = fmaf(bflo(v.y), q0.z, c2); c3 = fmaf(bfhi(v.y), q0.w, c3);         \
    c0 = fmaf(bflo(v.z), q1.x, c0); c1 = fmaf(bfhi(v.z), q1.y, c1);         \
    c2 = fmaf(bflo(v.w), q1.z, c2); c3 = fmaf(bfhi(v.w), q1.w, c3);         \
  }
        if (s < 12) {
          const uint4* el4 = elC + (s * 180 + res * 5);
          EL_BODY(el4)
        } else {
          const uint4* el4 = (const uint4*)elB + ((size_t)(s * 32 + b) * 180 + res * 5);
          EL_BODY(el4)
        }
        if (sr >= 20) {
          const uint4* er4 = erC + ((sr - 20) * 180 + res * 5);
          ER_BODY(er4)
        } else {
          const uint4* er4 = (const uint4*)erB + ((size_t)(sr * 32 + b) * 180 + res * 5);
          ER_BODY(er4)
        }
#undef EL_BODY
#undef ER_BODY
        if (res < 4 && L >= 3) {
          const float4* ecl = (const float4*)(Ec1lT + s * 16 + res * 4);
          const float4* ecr = (const float4*)(Ec1rT + sr * 16 + res * 4);
          float4 e0 = ecl[0], pb = dB4[5 + res];
          float4 e1 = ecr[0], pa = dA4[1 + res];
          b0 = fmaf(e0.x, pb.x, b0); b1 = fmaf(e0.y, pb.y, b1);
          b2 = fmaf(e0.z, pb.z, b2); b3 = fmaf(e0.w, pb.w, b3);
          c0 = fmaf(e1.x, pa.x, c0); c1 = fmaf(e1.y, pa.y, c1);
          c2 = fmaf(e1.z, pa.z, c2); c3 = fmaf(e1.w, pa.w, c3);
        }
        float val = fBs[s] * ((b0 + b1) + (b2 + b3))
                  + fAs[s] * ((c0 + c1) + (c2 + c3));
        D[offL + o] = val;
        unsigned int vb_ = __float_as_uint(val);
        if (vb_ > candb[par][s]) atomicMax(&candb[par][s], vb_);
      } else {
        int o2 = o - tot;
        int grp = o2 / (4 * S);
        int rem = o2 - grp * 4 * S;
        int s = rem >> 2, res = rem & 3;
        float4 egl = ((const float4*)eGlT)[res];
        float4 egr = ((const float4*)eGrT)[res];
        float Mn = Mt[offML + s];
        float mv = 0.f;
        int kbase = grp * 4 + 2;
#pragma unroll 1
        for (int kk = 0; kk < 4; kk++) {
          int k = kbase + kk;
          if (k > L - 2) break;
          int lk = L - k;
          int tk = ((k - 1) * (66 - k)) >> 1;
          int tl = ((lk - 1) * (66 - lk)) >> 1;
          const float4* Dk4 = (const float4*)(D + 36 * tk + s * 36);
          const float4* Dl4 = (const float4*)(D + 36 * tl + (s + k) * 36);
          float4 dk0 = Dk4[0], dkh = Dk4[1 + res];
          float4 dl0 = Dl4[0], dlh = Dl4[5 + res];
          float f = EXP2F(Mt[tk + s] + Mt[tl + s + k] - Mn);
          float sub = dk0.x * dlh.x * egl.x + dk0.y * dlh.y * egl.y
                    + dk0.z * dlh.z * egl.z + dk0.w * dlh.w * egl.w
                    + dl0.x * dkh.x * egr.x + dl0.y * dkh.y * egr.y
                    + dl0.z * dkh.z * egr.z + dl0.w * dkh.w * egr.w;
          mv = fmaf(f, sub, mv);
        }
        atomicAdd(&MIDacc[rem], mv);
      }
    }
    __syncthreads();

    // ---- phase 3: merge mids into D (res<4 columns)
    if (L >= 4) {
      for (int o = tid; o < 4 * S; o += 1024) {
        int s = o >> 2;
        float nv = D[offL + s * 36 + (o & 3)] + MIDacc[o];
        D[offL + s * 36 + (o & 3)] = nv;
        unsigned int vb_ = __float_as_uint(nv);
        if (vb_ > candb[par][s]) atomicMax(&candb[par][s], vb_);
      }
    }
    __syncthreads();
  }

  int wid = tid >> 6, lane = tid & 63;
  if (wid == 0) {
    int off32 = 36 * ((31 * 34) >> 1);
    float v = (lane < 36) ? D[off32 + lane] * EXP2F(root36[lane]) : 0.f;
#pragma unroll
    for (int w = 32; w > 0; w >>= 1) v += __shfl_xor(v, w);
    if (lane == 0) out[b] = -(Mt[527] + __log2f(v)) * LN2F;
  }
}

// ---------------------------------------------------------------------------
extern "C" void kernel_launch(void* const* d_in, const int* in_sizes, int n_in,
                              void* d_out, int out_size, void* d_ws, size_t ws_size,
                              hipStream_t stream) {
  const int*   x       = (const int*)d_in[0];
  const int*   lf_t    = (const int*)d_in[1];
  const int*   rf_t    = (const int*)d_in[2];
  const float* root_W  = (const float*)d_in[3];
  const float* root_b  = (const float*)d_in[4];
  const float* rule_W  = (const float*)d_in[5];
  const float* rule_b  = (const float*)d_in[6];
  const float* nt_emb  = (const float*)d_in[7];
  const float* sW1     = (const float*)d_in[8];
  const float* sb1     = (const float*)d_in[9];
  const float* r1W1    = (const float*)d_in[10];
  const float* r1b1    = (const float*)d_in[11];
  const float* r1W2    = (const float*)d_in[12];
  const float* r1b2    = (const float*)d_in[13];
  const float* r2W1    = (const float*)d_in[14];
  const float* r2b1    = (const float*)d_in[15];
  const float* r2W2    = (const float*)d_in[16];
  const float* r2b2    = (const float*)d_in[17];
  const float* sW2     = (const float*)d_in[18];
  const float* sb2     = (const float*)d_in[19];
  const float* vocab_W = (const float*)d_in[20];
  const float* vocab_b = (const float*)d_in[21];
  float* outp = (float*)d_out;

  float* ws = (float*)d_ws;
  float* split0 = ws;                         // 2596
  float* split1 = ws + 2596;                  // 2596
  float* Gl     = ws + 5192;                  // 1296
  float* Gr     = ws + 6488;                  // 1296
  float* root36 = ws + 7784;                  // 64
  float* lseacc = ws + 7848;                  // 2596 (pad to 2600)
  float* vbt    = ws + 10448;                 // 1024
  float* beta1  = ws + 11472;                 // 2658304 -> end 2669776
  uint32_t* elB = (uint32_t*)(ws + 2669776);  // 737280 -> end 3407056
  uint32_t* erB = (uint32_t*)(ws + 3407056);  // 737280 -> end 4144336
  // Wt overlays elB/erB region: consumed by k_lse_mfma BEFORE k_edge writes.
  uint4* Wt     = (uint4*)(ws + 2669776);     // 256000 uint4
  uint4* Bt     = (uint4*)(ws + 4144336);     // 8192 uint4 -> end 4177104

  k_front<<<1719, 256, 0, stream>>>(nt_emb, sW1, sb1, r1W1, r1b1, r1W2, r1b2,
                                    r2W1, r2b1, r2W2, r2b2, sW2, sb2,
                                    vocab_W, vocab_b, x,
                                    rule_W, rule_b, root_W, root_b,
                                    split0, split1, Wt, Bt, vbt, lseacc,
                                    Gl, Gr, root36);
  k_lse_mfma<<<dim3(25, 21), 256, 0, stream>>>(nt_emb, Wt, vocab_b, lseacc);
  k_beta1_mfma<<<dim3(41, 8), 256, 0, stream>>>(nt_emb, Bt, vbt, lseacc, split1, beta1);
  k_edge<<<1024, 256, 0, stream>>>(beta1, lf_t, rf_t, Gl, Gr, split0, elB, erB);
  k_cky<<<32, 1024, 0, stream>>>(beta1, elB, erB, Gl, Gr, split0, root36, outp);
}